// Round 8
// baseline (3097.062 us; speedup 1.0000x reference)
//
#include <hip/hip_runtime.h>
#include <stdint.h>

#define DEV static __device__ __forceinline__

typedef float          f32x4  __attribute__((ext_vector_type(4)));
typedef short          bf16x8 __attribute__((ext_vector_type(8)));
typedef unsigned short u16x4  __attribute__((ext_vector_type(4)));
typedef unsigned short u16x8  __attribute__((ext_vector_type(8)));

#define B_   2
#define T_   8192
#define D_   1024
#define H_   8
#define HD_  128
#define N_   128   /* chunks per (b,h) */

DEV float dot4(const float4& a, const float4& b) {
    return a.x * b.x + a.y * b.y + a.z * b.z + a.w * b.w;
}
DEV unsigned short f2bf(float f) {
    union { float f; unsigned u; } v; v.f = f;
    unsigned r = (v.u + 0x7fffu + ((v.u >> 16) & 1u)) >> 16;
    return (unsigned short)r;
}
DEV float bf2f(unsigned short u) {
    union { unsigned u; float f; } v; v.u = ((unsigned)u) << 16;
    return v.f;
}
DEV void cvt4(const float4 v, u16x4* h, u16x4* l) {
    const float* p = (const float*)&v;
    #pragma unroll
    for (int i = 0; i < 4; ++i) {
        unsigned short hv = f2bf(p[i]);
        (*h)[i] = hv;
        (*l)[i] = f2bf(p[i] - bf2f(hv));
    }
}
// Swizzled LDS rows of 512B (128 f32); swizzle per 16B unit: unit ^= (row&7).
DEV float4* r512(char* base, int r, int u) {
    return (float4*)(base + (r << 9) + ((u << 4) ^ ((r & 7) << 4)));
}
DEV float ld_sk(char* base, int c, int dk) {  // scalar read from swizzled [c][dk] f32 tile
    return *(float*)(base + (c << 9) + ((((dk >> 2) << 4) ^ ((c & 7) << 4)) + ((dk & 3) << 2)));
}

// =====================================================================
// Kernel 1: prep — L2-normalized k per head -> bf16 hi/lo [c][dk]; beta.
// =====================================================================
__launch_bounds__(256)
__global__ void prep_kernel(const float* __restrict__ X, const float* __restrict__ Wb,
                            unsigned short* __restrict__ khi, unsigned short* __restrict__ klo,
                            float* __restrict__ beta) {
    int bt = blockIdx.x;
    int b = bt >> 13, t = bt & 8191;
    __shared__ float xrow[D_];
    const float* xp = X + (size_t)bt * D_;
    for (int i = threadIdx.x; i < D_; i += 256) xrow[i] = xp[i];
    __syncthreads();
    int w = threadIdx.x >> 6, lane = threadIdx.x & 63;
    for (int h = w; h < H_; h += 4) {
        const float* xh = xrow + h * HD_;
        float a0 = xh[lane], a1 = xh[lane + 64];
        float s = a0 * a0 + a1 * a1;
        #pragma unroll
        for (int off = 32; off > 0; off >>= 1) s += __shfl_xor(s, off);
        float rn = 1.0f / fmaxf(sqrtf(s), 1e-12f);
        const float* wbh = Wb + (size_t)h * D_;
        float bs = 0.f;
        for (int i = lane; i < D_; i += 64) bs += xrow[i] * wbh[i];
        #pragma unroll
        for (int off = 32; off > 0; off >>= 1) bs += __shfl_xor(bs, off);
        float bet = 1.0f / (1.0f + expf(-bs));
        size_t kbase = ((size_t)(b * H_ + h) * T_ + t) * HD_;
        float x0 = a0 * rn, x1 = a1 * rn;
        unsigned short h0 = f2bf(x0), h1 = f2bf(x1);
        khi[kbase + lane]      = h0;
        khi[kbase + lane + 64] = h1;
        klo[kbase + lane]      = f2bf(x0 - bf2f(h0));
        klo[kbase + lane + 64] = f2bf(x1 - bf2f(h1));
        if (lane == 0) beta[(size_t)(b * H_ + h) * T_ + t] = bet;
    }
}

// =====================================================================
// Kernel 2: vproj — v = beta*(x @ W_write^T) via split-bf16 MFMA (f32 out)
// =====================================================================
__launch_bounds__(256, 2)
__global__ void vproj_kernel(const float* __restrict__ X, const float* __restrict__ W,
                             const float* __restrict__ beta, float* __restrict__ vb) {
    extern __shared__ char gs[];
    char* AH = gs;             // [128][64] bf16 hi, swizzled, 16KB
    char* AL = gs + 16384;
    char* BH = gs + 32768;
    char* BL = gs + 49152;     // 64KB
    int bm = blockIdx.x, bn = blockIdx.y;
    int tid = threadIdx.x;
    int w = tid >> 6, lr = tid & 15, lk = (tid & 63) >> 4;
    int wm = w >> 1, wn = w & 1;

    f32x4 acc[4][4];
    #pragma unroll
    for (int i = 0; i < 4; ++i)
        #pragma unroll
        for (int j = 0; j < 4; ++j) acc[i][j] = (f32x4){0.f, 0.f, 0.f, 0.f};

    for (int kt = 0; kt < 16; ++kt) {
        __syncthreads();
        #pragma unroll
        for (int q = 0; q < 8; ++q) {
            int f = tid + q * 256;
            int row = f >> 4, kq = f & 15;
            float4 av = *(const float4*)(X + (size_t)(bm * 128 + row) * D_ + kt * 64 + kq * 4);
            float4 bv = *(const float4*)(W + (size_t)(bn * 128 + row) * D_ + kt * 64 + kq * 4);
            u16x4 ah, al, bh, bl;
            cvt4(av, &ah, &al);
            cvt4(bv, &bh, &bl);
            int off = row * 128 + ((((kq >> 1) ^ (row & 7))) << 4) + ((kq & 1) << 3);
            *(u16x4*)(AH + off) = ah; *(u16x4*)(AL + off) = al;
            *(u16x4*)(BH + off) = bh; *(u16x4*)(BL + off) = bl;
        }
        __syncthreads();
        #pragma unroll
        for (int ks = 0; ks < 2; ++ks) {
            bf16x8 aH[4], aL[4], bH[4], bL[4];
            #pragma unroll
            for (int mt = 0; mt < 4; ++mt) {
                int row = wm * 64 + mt * 16 + lr;
                int off = row * 128 + (((ks * 4 + lk) ^ (row & 7)) << 4);
                aH[mt] = *(const bf16x8*)(AH + off);
                aL[mt] = *(const bf16x8*)(AL + off);
            }
            #pragma unroll
            for (int nt = 0; nt < 4; ++nt) {
                int row = wn * 64 + nt * 16 + lr;
                int off = row * 128 + (((ks * 4 + lk) ^ (row & 7)) << 4);
                bH[nt] = *(const bf16x8*)(BH + off);
                bL[nt] = *(const bf16x8*)(BL + off);
            }
            #pragma unroll
            for (int mt = 0; mt < 4; ++mt)
                #pragma unroll
                for (int nt = 0; nt < 4; ++nt) {
                    acc[mt][nt] = __builtin_amdgcn_mfma_f32_16x16x32_bf16(aH[mt], bH[nt], acc[mt][nt], 0, 0, 0);
                    acc[mt][nt] = __builtin_amdgcn_mfma_f32_16x16x32_bf16(aH[mt], bL[nt], acc[mt][nt], 0, 0, 0);
                    acc[mt][nt] = __builtin_amdgcn_mfma_f32_16x16x32_bf16(aL[mt], bH[nt], acc[mt][nt], 0, 0, 0);
                }
        }
    }
    #pragma unroll
    for (int mt = 0; mt < 4; ++mt)
        #pragma unroll
        for (int r = 0; r < 4; ++r) {
            int m = bm * 128 + wm * 64 + mt * 16 + lk * 4 + r;
            int b = m >> 13, t = m & 8191;
            float bet = beta[(size_t)(b * H_ + bn) * T_ + t];
            size_t ob = ((size_t)(b * H_ + bn) * T_ + t) * HD_;
            #pragma unroll
            for (int nt = 0; nt < 4; ++nt)
                vb[ob + wn * 64 + nt * 16 + lr] = acc[mt][nt][r] * bet;
        }
}

// =====================================================================
// Kernel 3: chunk — dots, attn(bf16), M, A=M^{-1}, kcd-neg (hi/lo),
//   v' = A@v (f32 in place), kT emission [dk][c] hi (+lo if avail).
// =====================================================================
__launch_bounds__(256, 2)
__global__ void chunk_kernel(const unsigned short* __restrict__ khi,
                             const unsigned short* __restrict__ klo,
                             float* __restrict__ vb,
                             const float* __restrict__ beta_g,
                             const float* __restrict__ decay,
                             unsigned short* __restrict__ attn_g,
                             unsigned short* __restrict__ kcdhi_g,
                             unsigned short* __restrict__ kcdlo_g,
                             unsigned short* __restrict__ kThi_g,
                             unsigned short* __restrict__ kTlo_g) {
    extern __shared__ char cs[];
    char*  sk = cs;                      // [64][128] f32 swz (32KB); later reused for v
    float* sa = (float*)(cs + 32768);    // [64][64] A
    float* sm = (float*)(cs + 49152);    // [64][64] M
    __shared__ float sb[64];
    __shared__ float swgt[64];

    int cid = blockIdx.x;
    int bh = cid >> 7, cn = cid & 127;
    int h = bh & 7;
    int tid = threadIdx.x;
    float dec = decay[h];
    float sg = 1.0f / (1.0f + expf(-dec));
    float lg = logf(sg);
    size_t base = (size_t)cid * 8192;

    #pragma unroll
    for (int lq = 0; lq < 4; ++lq) {
        int f = tid + lq * 256;
        int c = f >> 4, u0 = (f & 15) << 1;
        u16x8 hh = *(const u16x8*)(khi + base + (size_t)f * 8);
        u16x8 ll = *(const u16x8*)(klo + base + (size_t)f * 8);
        float4 v0 = {bf2f(hh[0]) + bf2f(ll[0]), bf2f(hh[1]) + bf2f(ll[1]),
                     bf2f(hh[2]) + bf2f(ll[2]), bf2f(hh[3]) + bf2f(ll[3])};
        float4 v1 = {bf2f(hh[4]) + bf2f(ll[4]), bf2f(hh[5]) + bf2f(ll[5]),
                     bf2f(hh[6]) + bf2f(ll[6]), bf2f(hh[7]) + bf2f(ll[7])};
        *r512(sk, c, u0)     = v0;
        *r512(sk, c, u0 + 1) = v1;
    }
    if (tid < 64) {
        float bv = beta_g[(size_t)bh * T_ + cn * 64 + tid];
        sb[tid] = bv;
        swgt[tid] = bv * expf((float)(tid + 1) * lg);
    }
    __syncthreads();

    int bi = tid >> 4, bj = tid & 15;
    float dacc[4][4] = {};
    for (int u = 0; u < 32; ++u) {
        float4 ka[4], kc[4];
        #pragma unroll
        for (int i = 0; i < 4; ++i) ka[i] = *r512(sk, bi * 4 + i, u);
        #pragma unroll
        for (int j = 0; j < 4; ++j) kc[j] = *r512(sk, bj + 16 * j, u);
        #pragma unroll
        for (int i = 0; i < 4; ++i)
            #pragma unroll
            for (int j = 0; j < 4; ++j)
                dacc[i][j] += dot4(ka[i], kc[j]);
    }
    size_t abase = (size_t)cid * 4096;
    #pragma unroll
    for (int i = 0; i < 4; ++i) {
        int gi = bi * 4 + i;
        #pragma unroll
        for (int j = 0; j < 4; ++j) {
            int gj = bj + 16 * j;
            float dv = dacc[i][j];
            float dfac = expf((float)(gi - gj) * lg);
            attn_g[abase + (size_t)gi * 64 + gj] = (gi >= gj) ? f2bf(dv * dfac) : (unsigned short)0;
            sm[gi * 64 + gj] = (gj < gi) ? sb[gi] * dv * dfac : ((gi == gj) ? 1.f : 0.f);
        }
    }
    __syncthreads();

    if (tid < 64) {
        int j = tid;
        for (int i = 0; i < j; ++i) sa[i * 64 + j] = 0.f;
        sa[j * 64 + j] = 1.f;
        for (int i = j + 1; i < 64; ++i) {
            float s = 0.f;
            for (int p = j; p < i; ++p) s += sm[i * 64 + p] * sa[p * 64 + j];
            sa[i * 64 + j] = -s;
        }
    }
    __syncthreads();

    int ti = tid >> 4, te = tid & 15;
    {   // kcd(negated) hi/lo
        float ko[4][8] = {};
        for (int p = 0; p < 64; ++p) {
            float w = swgt[p];
            float4 k0 = *r512(sk, p, te * 2);
            float4 k1 = *r512(sk, p, te * 2 + 1);
            float kv[8] = {k0.x, k0.y, k0.z, k0.w, k1.x, k1.y, k1.z, k1.w};
            float a0 = sa[(ti * 4 + 0) * 64 + p] * w;
            float a1 = sa[(ti * 4 + 1) * 64 + p] * w;
            float a2 = sa[(ti * 4 + 2) * 64 + p] * w;
            float a3 = sa[(ti * 4 + 3) * 64 + p] * w;
            #pragma unroll
            for (int e = 0; e < 8; ++e) {
                ko[0][e] = fmaf(a0, kv[e], ko[0][e]);
                ko[1][e] = fmaf(a1, kv[e], ko[1][e]);
                ko[2][e] = fmaf(a2, kv[e], ko[2][e]);
                ko[3][e] = fmaf(a3, kv[e], ko[3][e]);
            }
        }
        #pragma unroll
        for (int i = 0; i < 4; ++i) {
            u16x8 hh, ll;
            #pragma unroll
            for (int e = 0; e < 8; ++e) {
                float t = -ko[i][e];
                unsigned short hv = f2bf(t);
                hh[e] = hv;
                ll[e] = f2bf(t - bf2f(hv));
            }
            size_t off = base + (size_t)(ti * 4 + i) * 128 + te * 8;
            *(u16x8*)(kcdhi_g + off) = hh;
            *(u16x8*)(kcdlo_g + off) = ll;
        }
    }

    // ---- kT emission: kThi[dk][c] (+kTlo). sk still holds k. ----
    {
        int dk = tid >> 1, ch = (tid & 1) * 32;
        #pragma unroll
        for (int q = 0; q < 4; ++q) {
            u16x8 th, tl;
            #pragma unroll
            for (int j = 0; j < 8; ++j) {
                float kv = ld_sk(sk, ch + q * 8 + j, dk);
                unsigned short hv = f2bf(kv);
                th[j] = hv;
                tl[j] = f2bf(kv - bf2f(hv));
            }
            size_t off = base + (size_t)dk * 64 + ch + q * 8;
            *(u16x8*)(kThi_g + off) = th;
            if (kTlo_g) *(u16x8*)(kTlo_g + off) = tl;
        }
    }
    __syncthreads();

    #pragma unroll
    for (int lq = 0; lq < 8; ++lq) {
        int f = tid + lq * 256;
        int r = f >> 5, u = f & 31;
        *r512(sk, r, u) = ((const float4*)(vb + base))[f];
    }
    __syncthreads();

    {   // v' = A @ v (in place)
        float vo[4][8] = {};
        for (int p = 0; p < 64; ++p) {
            float4 v0 = *r512(sk, p, te * 2);
            float4 v1 = *r512(sk, p, te * 2 + 1);
            float vv[8] = {v0.x, v0.y, v0.z, v0.w, v1.x, v1.y, v1.z, v1.w};
            float a0 = sa[(ti * 4 + 0) * 64 + p];
            float a1 = sa[(ti * 4 + 1) * 64 + p];
            float a2 = sa[(ti * 4 + 2) * 64 + p];
            float a3 = sa[(ti * 4 + 3) * 64 + p];
            #pragma unroll
            for (int e = 0; e < 8; ++e) {
                vo[0][e] = fmaf(a0, vv[e], vo[0][e]);
                vo[1][e] = fmaf(a1, vv[e], vo[1][e]);
                vo[2][e] = fmaf(a2, vv[e], vo[2][e]);
                vo[3][e] = fmaf(a3, vv[e], vo[3][e]);
            }
        }
        #pragma unroll
        for (int i = 0; i < 4; ++i) {
            float4 lo = {vo[i][0], vo[i][1], vo[i][2], vo[i][3]};
            float4 hi = {vo[i][4], vo[i][5], vo[i][6], vo[i][7]};
            size_t off = base + (size_t)(ti * 4 + i) * 128 + te * 8;
            *(float4*)(vb + off)     = lo;
            *(float4*)(vb + off + 4) = hi;
        }
    }
}

// =====================================================================
// Kernel 4: scan v5 — ONE WAVE PER CHAIN, zero barriers.
// grid 128 = 16 bh x 8 e-strips(16), 64 thr. Wave owns S[dk 128][e 16]
// as 8 f32x4 C-frags; S/vnew transposed to B-frags via private LDS
// (same-wave lgkmcnt ordering only). A-operands direct from global.
// o written f32 IN PLACE over v' (vb).
// =====================================================================
__launch_bounds__(64, 1)
__global__ void scan_kernel(const unsigned short* __restrict__ khi,
                            const unsigned short* __restrict__ klo,
                            float* __restrict__ vb,
                            const unsigned short* __restrict__ kcdh,
                            const unsigned short* __restrict__ kcdl,
                            const unsigned short* __restrict__ att,
                            const unsigned short* __restrict__ kThi,
                            const unsigned short* __restrict__ kTlo,
                            const float* __restrict__ decay) {
    __shared__ char SH[4096];   // S^T hi  [e:16][dk:128] bf16, unit-swizzled
    __shared__ char SL[4096];
    __shared__ char VH[2048];   // vnew^T      [e:16][c:64]
    __shared__ char VL[2048];
    __shared__ char WH[2048];   // vnew^T * gamma^{63-c}
    __shared__ char WL[2048];

    int bid = blockIdx.x;
    int bh = ((bid >> 6) << 3) + (bid & 7);   // same-h blocks share an XCD
    int strip = (bid >> 3) & 7;
    int e0 = strip * 16;
    int l = threadIdx.x & 63;
    int lr = l & 15, lk = l >> 4;
    float dec = decay[bh & 7];
    float sg = 1.0f / (1.0f + expf(-dec));
    float lg = logf(sg);
    float g64 = expf(64.f * lg);
    float devv[4][4], gww[4][4];
    #pragma unroll
    for (int ct = 0; ct < 4; ++ct)
        #pragma unroll
        for (int r = 0; r < 4; ++r) {
            int c = ct * 16 + lk * 4 + r;
            devv[ct][r] = expf((float)(c + 1) * lg);
            gww[ct][r]  = expf((float)(63 - c) * lg);
        }
    const bool haveLo = (kTlo != nullptr);

    f32x4 Sacc[8];
    #pragma unroll
    for (int dt = 0; dt < 8; ++dt) Sacc[dt] = (f32x4){0.f, 0.f, 0.f, 0.f};

    for (int cn = 0; cn < N_; ++cn) {
        size_t cid = (size_t)bh * N_ + cn;
        size_t cb8 = cid * 8192, cb4 = cid * 4096;

        // ---- publish S hi/lo (8 dk-tiles, this wave only) ----
        #pragma unroll
        for (int dt = 0; dt < 8; ++dt) {
            u16x4 h4, l4;
            #pragma unroll
            for (int r = 0; r < 4; ++r) {
                unsigned short hv = f2bf(Sacc[dt][r]);
                h4[r] = hv;
                l4[r] = f2bf(Sacc[dt][r] - bf2f(hv));
            }
            int unit = 2 * dt + (lk >> 1);
            int off = lr * 256 + ((unit ^ (lr & 7)) << 4) + ((lk & 1) << 3);
            *(u16x4*)(SH + off) = h4;
            *(u16x4*)(SL + off) = l4;
        }
        // ---- S B-frags ----
        bf16x8 BH[4], BL[4];
        #pragma unroll
        for (int s = 0; s < 4; ++s) {
            int off = lr * 256 + (((s * 4 + lk) ^ (lr & 7)) << 4);
            BH[s] = *(const bf16x8*)(SH + off);
            BL[s] = *(const bf16x8*)(SL + off);
        }

        // ---- Pass A: M1 per c-tile -> publish vnew (plain + scaled) ----
        #pragma unroll
        for (int ct = 0; ct < 4; ++ct) {
            bf16x8 cdH[4], cdL[4];
            #pragma unroll
            for (int ks = 0; ks < 4; ++ks) {
                size_t off = cb8 + (size_t)(ct * 16 + lr) * 128 + ks * 32 + lk * 8;
                cdH[ks] = *(const bf16x8*)(kcdh + off);
                cdL[ks] = *(const bf16x8*)(kcdl + off);
            }
            f32x4 vn, vn2 = (f32x4){0.f, 0.f, 0.f, 0.f};
            #pragma unroll
            for (int r = 0; r < 4; ++r)
                vn[r] = vb[cb8 + (size_t)(ct * 16 + lk * 4 + r) * 128 + e0 + lr];
            #pragma unroll
            for (int ks = 0; ks < 2; ++ks) {
                vn  = __builtin_amdgcn_mfma_f32_16x16x32_bf16(cdH[ks],   BH[ks],   vn,  0, 0, 0);
                vn2 = __builtin_amdgcn_mfma_f32_16x16x32_bf16(cdH[ks+2], BH[ks+2], vn2, 0, 0, 0);
                vn  = __builtin_amdgcn_mfma_f32_16x16x32_bf16(cdH[ks],   BL[ks],   vn,  0, 0, 0);
                vn2 = __builtin_amdgcn_mfma_f32_16x16x32_bf16(cdH[ks+2], BL[ks+2], vn2, 0, 0, 0);
                vn  = __builtin_amdgcn_mfma_f32_16x16x32_bf16(cdL[ks],   BH[ks],   vn,  0, 0, 0);
                vn2 = __builtin_amdgcn_mfma_f32_16x16x32_bf16(cdL[ks+2], BH[ks+2], vn2, 0, 0, 0);
            }
            u16x4 h4, l4, wh4, wl4;
            #pragma unroll
            for (int r = 0; r < 4; ++r) {
                float vv = vn[r] + vn2[r];
                unsigned short hv = f2bf(vv);
                h4[r] = hv; l4[r] = f2bf(vv - bf2f(hv));
                float wv = vv * gww[ct][r];
                unsigned short wh = f2bf(wv);
                wh4[r] = wh; wl4[r] = f2bf(wv - bf2f(wh));
            }
            int cu = 2 * ct + (lk >> 1);
            int off = lr * 128 + ((cu ^ (lr & 7)) << 4) + ((lk & 1) << 3);
            *(u16x4*)(VH + off) = h4;  *(u16x4*)(VL + off) = l4;
            *(u16x4*)(WH + off) = wh4; *(u16x4*)(WL + off) = wl4;
        }
        // ---- vnew / W B-frags ----
        bf16x8 VHf[2], VLf[2], WHf[2], WLf[2];
        #pragma unroll
        for (int s2 = 0; s2 < 2; ++s2) {
            int off = lr * 128 + (((s2 * 4 + lk) ^ (lr & 7)) << 4);
            VHf[s2] = *(const bf16x8*)(VH + off);
            VLf[s2] = *(const bf16x8*)(VL + off);
            WHf[s2] = *(const bf16x8*)(WH + off);
            WLf[s2] = *(const bf16x8*)(WL + off);
        }

        // ---- Pass B: o = dev*(k@S) + att@vnew ; store f32 over v' ----
        #pragma unroll
        for (int ct = 0; ct < 4; ++ct) {
            bf16x8 kH[4], kL[4], atA[2];
            #pragma unroll
            for (int ks = 0; ks < 4; ++ks) {
                size_t off = cb8 + (size_t)(ct * 16 + lr) * 128 + ks * 32 + lk * 8;
                kH[ks] = *(const bf16x8*)(khi + off);
                kL[ks] = *(const bf16x8*)(klo + off);
            }
            #pragma unroll
            for (int s2 = 0; s2 < 2; ++s2)
                atA[s2] = *(const bf16x8*)(att + cb4 + (size_t)(ct * 16 + lr) * 64 + s2 * 32 + lk * 8);
            f32x4 oa = (f32x4){0.f, 0.f, 0.f, 0.f}, ob = oa;
            #pragma unroll
            for (int ks = 0; ks < 2; ++ks) {
                oa = __builtin_amdgcn_mfma_f32_16x16x32_bf16(kH[ks],   BH[ks],   oa, 0, 0, 0);
                ob = __builtin_amdgcn_mfma_f32_16x16x32_bf16(kH[ks+2], BH[ks+2], ob, 0, 0, 0);
                oa = __builtin_amdgcn_mfma_f32_16x16x32_bf16(kH[ks],   BL[ks],   oa, 0, 0, 0);
                ob = __builtin_amdgcn_mfma_f32_16x16x32_bf16(kH[ks+2], BL[ks+2], ob, 0, 0, 0);
                oa = __builtin_amdgcn_mfma_f32_16x16x32_bf16(kL[ks],   BH[ks],   oa, 0, 0, 0);
                ob = __builtin_amdgcn_mfma_f32_16x16x32_bf16(kL[ks+2], BH[ks+2], ob, 0, 0, 0);
            }
            f32x4 om;
            #pragma unroll
            for (int r = 0; r < 4; ++r) om[r] = (oa[r] + ob[r]) * devv[ct][r];
            #pragma unroll
            for (int s2 = 0; s2 < 2; ++s2) {
                om = __builtin_amdgcn_mfma_f32_16x16x32_bf16(atA[s2], VHf[s2], om, 0, 0, 0);
                om = __builtin_amdgcn_mfma_f32_16x16x32_bf16(atA[s2], VLf[s2], om, 0, 0, 0);
            }
            #pragma unroll
            for (int r = 0; r < 4; ++r)
                vb[cb8 + (size_t)(ct * 16 + lk * 4 + r) * 128 + e0 + lr] = om[r];
        }

        // ---- Pass C: S = g64*S + kT @ W  (8 dk-tiles, interleaved pairs) ----
        #pragma unroll
        for (int dp = 0; dp < 4; ++dp) {
            int d0 = dp * 2, d1 = dp * 2 + 1;
            bf16x8 t0H[2], t1H[2], t0L[2], t1L[2];
            #pragma unroll
            for (int s2 = 0; s2 < 2; ++s2) {
                size_t o0 = cb8 + (size_t)(d0 * 16 + lr) * 64 + s2 * 32 + lk * 8;
                size_t o1 = cb8 + (size_t)(d1 * 16 + lr) * 64 + s2 * 32 + lk * 8;
                t0H[s2] = *(const bf16x8*)(kThi + o0);
                t1H[s2] = *(const bf16x8*)(kThi + o1);
                if (haveLo) {
                    t0L[s2] = *(const bf16x8*)(kTlo + o0);
                    t1L[s2] = *(const bf16x8*)(kTlo + o1);
                }
            }
            f32x4 s0 = Sacc[d0], s1 = Sacc[d1];
            #pragma unroll
            for (int r = 0; r < 4; ++r) { s0[r] *= g64; s1[r] *= g64; }
            #pragma unroll
            for (int s2 = 0; s2 < 2; ++s2) {
                s0 = __builtin_amdgcn_mfma_f32_16x16x32_bf16(t0H[s2], WHf[s2], s0, 0, 0, 0);
                s1 = __builtin_amdgcn_mfma_f32_16x16x32_bf16(t1H[s2], WHf[s2], s1, 0, 0, 0);
                s0 = __builtin_amdgcn_mfma_f32_16x16x32_bf16(t0H[s2], WLf[s2], s0, 0, 0, 0);
                s1 = __builtin_amdgcn_mfma_f32_16x16x32_bf16(t1H[s2], WLf[s2], s1, 0, 0, 0);
                if (haveLo) {
                    s0 = __builtin_amdgcn_mfma_f32_16x16x32_bf16(t0L[s2], WHf[s2], s0, 0, 0, 0);
                    s1 = __builtin_amdgcn_mfma_f32_16x16x32_bf16(t1L[s2], WHf[s2], s1, 0, 0, 0);
                }
            }
            Sacc[d0] = s0; Sacc[d1] = s1;
        }
    }
}

// =====================================================================
// Kernel 5: final — out = x + o @ W_read^T. o is f32 (in vb), 3-product.
// grid (128, 8) x 256 thr. dyn LDS 64KB.
// =====================================================================
__launch_bounds__(256, 2)
__global__ void final_kernel(const float* __restrict__ X, const float* __restrict__ W,
                             const float* __restrict__ OB, float* __restrict__ out) {
    extern __shared__ char gs[];
    char* AH = gs;             // [128][64] bf16 hi, swizzled, 16KB
    char* AL = gs + 16384;
    char* BH = gs + 32768;
    char* BL = gs + 49152;     // 64KB
    int bm = blockIdx.x, bn = blockIdx.y;
    int tid = threadIdx.x;
    int w = tid >> 6, lr = tid & 15, lk = (tid & 63) >> 4;
    int wm = w >> 1, wn = w & 1;

    f32x4 acc[4][4];
    #pragma unroll
    for (int i = 0; i < 4; ++i)
        #pragma unroll
        for (int j = 0; j < 4; ++j) acc[i][j] = (f32x4){0.f, 0.f, 0.f, 0.f};

    for (int kt = 0; kt < 16; ++kt) {
        int hh = kt >> 1, e0g = (kt & 1) * 64;
        __syncthreads();
        #pragma unroll
        for (int q = 0; q < 8; ++q) {
            int f = tid + q * 256;
            int row = f >> 4, kq = f & 15;
            int m = bm * 128 + row;
            int b = m >> 13, t = m & 8191;
            float4 av = *(const float4*)(OB + (((size_t)(b * H_ + hh) * T_ + t) << 7) + e0g + kq * 4);
            float4 bv = *(const float4*)(W + (size_t)(bn * 128 + row) * D_ + kt * 64 + kq * 4);
            u16x4 ah, al, bh, bl;
            cvt4(av, &ah, &al);
            cvt4(bv, &bh, &bl);
            int off = row * 128 + ((((kq >> 1) ^ (row & 7))) << 4) + ((kq & 1) << 3);
            *(u16x4*)(AH + off) = ah; *(u16x4*)(AL + off) = al;
            *(u16x4*)(BH + off) = bh; *(u16x4*)(BL + off) = bl;
        }
        __syncthreads();
        #pragma unroll
        for (int ks = 0; ks < 2; ++ks) {
            bf16x8 aH[4], aL[4], bH[4], bL[4];
            #pragma unroll
            for (int mt = 0; mt < 4; ++mt) {
                int row = wm * 64 + mt * 16 + lr;
                int off = row * 128 + (((ks * 4 + lk) ^ (row & 7)) << 4);
                aH[mt] = *(const bf16x8*)(AH + off);
                aL[mt] = *(const bf16x8*)(AL + off);
            }
            #pragma unroll
            for (int nt = 0; nt < 4; ++nt) {
                int row = wn * 64 + nt * 16 + lr;
                int off = row * 128 + (((ks * 4 + lk) ^ (row & 7)) << 4);
                bH[nt] = *(const bf16x8*)(BH + off);
                bL[nt] = *(const bf16x8*)(BL + off);
            }
            #pragma unroll
            for (int mt = 0; mt < 4; ++mt)
                #pragma unroll
                for (int nt = 0; nt < 4; ++nt) {
                    acc[mt][nt] = __builtin_amdgcn_mfma_f32_16x16x32_bf16(aH[mt], bH[nt], acc[mt][nt], 0, 0, 0);
                    acc[mt][nt] = __builtin_amdgcn_mfma_f32_16x16x32_bf16(aH[mt], bL[nt], acc[mt][nt], 0, 0, 0);
                    acc[mt][nt] = __builtin_amdgcn_mfma_f32_16x16x32_bf16(aL[mt], bH[nt], acc[mt][nt], 0, 0, 0);
                }
        }
    }
    #pragma unroll
    for (int mt = 0; mt < 4; ++mt)
        #pragma unroll
        for (int r = 0; r < 4; ++r) {
            int m = bm * 128 + wm * 64 + mt * 16 + lk * 4 + r;
            size_t xo = (size_t)m * D_ + bn * 128;
            #pragma unroll
            for (int nt = 0; nt < 4; ++nt) {
                int n = wn * 64 + nt * 16 + lr;
                out[xo + n] = X[xo + n] + acc[mt][nt][r];
            }
        }
}

// =====================================================================
extern "C" void kernel_launch(void* const* d_in, const int* in_sizes, int n_in,
                              void* d_out, int out_size, void* d_ws, size_t ws_size,
                              hipStream_t stream) {
    const float* X   = (const float*)d_in[0];
    const float* Ww  = (const float*)d_in[1];
    const float* Wr  = (const float*)d_in[2];
    const float* Wb  = (const float*)d_in[3];
    const float* dec = (const float*)d_in[4];

    // workspace layout (bytes). Base = 252,182,528 (proven). kTlo optional.
    char* ws = (char*)d_ws;
    unsigned short* khi  = (unsigned short*)(ws);                 // 32MB [c][dk] hi
    unsigned short* klo  = (unsigned short*)(ws + 33554432);      // 32MB
    float*          vb   = (float*)(ws + 67108864);               // 64MB  v -> v' -> o (f32)
    unsigned short* kcdh = (unsigned short*)(ws + 134217728);     // 32MB
    unsigned short* kcdl = (unsigned short*)(ws + 167772160);     // 32MB
    unsigned short* attn = (unsigned short*)(ws + 201326592);     // 16MB
    float*          beta = (float*)(ws + 218103808);              // 0.5MB
    unsigned short* kThi = (unsigned short*)(ws + 218628096);     // 32MB [dk][c] hi
    unsigned short* kTlo = (ws_size >= 285736960ull)
                         ? (unsigned short*)(ws + 252182528)      // 32MB [dk][c] lo (if room)
                         : (unsigned short*)nullptr;
    if (ws_size < 252182528ull) return;

    hipFuncSetAttribute((const void*)vproj_kernel, hipFuncAttributeMaxDynamicSharedMemorySize, 65536);
    hipFuncSetAttribute((const void*)chunk_kernel, hipFuncAttributeMaxDynamicSharedMemorySize, 65536);
    hipFuncSetAttribute((const void*)final_kernel, hipFuncAttributeMaxDynamicSharedMemorySize, 65536);

    hipLaunchKernelGGL(prep_kernel, dim3(B_ * T_), dim3(256), 0, stream, X, Wb, khi, klo, beta);
    hipLaunchKernelGGL(vproj_kernel, dim3(128, 8), dim3(256), 65536, stream, X, Ww, beta, vb);
    hipLaunchKernelGGL(chunk_kernel, dim3(B_ * H_ * N_), dim3(256), 65536, stream,
                       khi, klo, vb, beta, dec, attn, kcdh, kcdl, kThi, kTlo);
    hipLaunchKernelGGL(scan_kernel, dim3(128), dim3(64), 0, stream,
                       khi, klo, vb, kcdh, kcdl, attn, kThi, kTlo, dec);
    hipLaunchKernelGGL(final_kernel, dim3(128, 8), dim3(256), 65536, stream, X, Wr, vb, (float*)d_out);
}

// Round 9
// 1084.697 us; speedup vs baseline: 2.8552x; 2.8552x over previous
//
#include <hip/hip_runtime.h>
#include <stdint.h>

#define DEV static __device__ __forceinline__

typedef float          f32x4  __attribute__((ext_vector_type(4)));
typedef short          bf16x8 __attribute__((ext_vector_type(8)));
typedef unsigned short u16x4  __attribute__((ext_vector_type(4)));
typedef unsigned short u16x8  __attribute__((ext_vector_type(8)));

#define B_   2
#define T_   8192
#define D_   1024
#define H_   8
#define HD_  128
#define N_   128   /* chunks per (b,h) */

DEV float dot4(const float4& a, const float4& b) {
    return a.x * b.x + a.y * b.y + a.z * b.z + a.w * b.w;
}
DEV unsigned short f2bf(float f) {
    union { float f; unsigned u; } v; v.f = f;
    unsigned r = (v.u + 0x7fffu + ((v.u >> 16) & 1u)) >> 16;
    return (unsigned short)r;
}
DEV float bf2f(unsigned short u) {
    union { unsigned u; float f; } v; v.u = ((unsigned)u) << 16;
    return v.f;
}
DEV void cvt4(const float4 v, u16x4* h, u16x4* l) {
    const float* p = (const float*)&v;
    #pragma unroll
    for (int i = 0; i < 4; ++i) {
        unsigned short hv = f2bf(p[i]);
        (*h)[i] = hv;
        (*l)[i] = f2bf(p[i] - bf2f(hv));
    }
}
// Swizzled LDS rows of 512B (128 f32); swizzle per 16B unit: unit ^= (row&7).
DEV float4* r512(char* base, int r, int u) {
    return (float4*)(base + (r << 9) + ((u << 4) ^ ((r & 7) << 4)));
}
DEV float ld_sk(char* base, int c, int dk) {  // scalar read from swizzled [c][dk] f32 tile
    return *(float*)(base + (c << 9) + ((((dk >> 2) << 4) ^ ((c & 7) << 4)) + ((dk & 3) << 2)));
}

// =====================================================================
// Kernel 1: prep — L2-normalized k per head -> bf16 hi/lo [c][dk]; beta.
// =====================================================================
__launch_bounds__(256)
__global__ void prep_kernel(const float* __restrict__ X, const float* __restrict__ Wb,
                            unsigned short* __restrict__ khi, unsigned short* __restrict__ klo,
                            float* __restrict__ beta) {
    int bt = blockIdx.x;
    int b = bt >> 13, t = bt & 8191;
    __shared__ float xrow[D_];
    const float* xp = X + (size_t)bt * D_;
    for (int i = threadIdx.x; i < D_; i += 256) xrow[i] = xp[i];
    __syncthreads();
    int w = threadIdx.x >> 6, lane = threadIdx.x & 63;
    for (int h = w; h < H_; h += 4) {
        const float* xh = xrow + h * HD_;
        float a0 = xh[lane], a1 = xh[lane + 64];
        float s = a0 * a0 + a1 * a1;
        #pragma unroll
        for (int off = 32; off > 0; off >>= 1) s += __shfl_xor(s, off);
        float rn = 1.0f / fmaxf(sqrtf(s), 1e-12f);
        const float* wbh = Wb + (size_t)h * D_;
        float bs = 0.f;
        for (int i = lane; i < D_; i += 64) bs += xrow[i] * wbh[i];
        #pragma unroll
        for (int off = 32; off > 0; off >>= 1) bs += __shfl_xor(bs, off);
        float bet = 1.0f / (1.0f + expf(-bs));
        size_t kbase = ((size_t)(b * H_ + h) * T_ + t) * HD_;
        float x0 = a0 * rn, x1 = a1 * rn;
        unsigned short h0 = f2bf(x0), h1 = f2bf(x1);
        khi[kbase + lane]      = h0;
        khi[kbase + lane + 64] = h1;
        klo[kbase + lane]      = f2bf(x0 - bf2f(h0));
        klo[kbase + lane + 64] = f2bf(x1 - bf2f(h1));
        if (lane == 0) beta[(size_t)(b * H_ + h) * T_ + t] = bet;
    }
}

// =====================================================================
// Kernel 2: vproj — v = beta*(x @ W_write^T) via split-bf16 MFMA (f32 out)
// =====================================================================
__launch_bounds__(256, 2)
__global__ void vproj_kernel(const float* __restrict__ X, const float* __restrict__ W,
                             const float* __restrict__ beta, float* __restrict__ vb) {
    extern __shared__ char gs[];
    char* AH = gs;             // [128][64] bf16 hi, swizzled, 16KB
    char* AL = gs + 16384;
    char* BH = gs + 32768;
    char* BL = gs + 49152;     // 64KB
    int bm = blockIdx.x, bn = blockIdx.y;
    int tid = threadIdx.x;
    int w = tid >> 6, lr = tid & 15, lk = (tid & 63) >> 4;
    int wm = w >> 1, wn = w & 1;

    f32x4 acc[4][4];
    #pragma unroll
    for (int i = 0; i < 4; ++i)
        #pragma unroll
        for (int j = 0; j < 4; ++j) acc[i][j] = (f32x4){0.f, 0.f, 0.f, 0.f};

    for (int kt = 0; kt < 16; ++kt) {
        __syncthreads();
        #pragma unroll
        for (int q = 0; q < 8; ++q) {
            int f = tid + q * 256;
            int row = f >> 4, kq = f & 15;
            float4 av = *(const float4*)(X + (size_t)(bm * 128 + row) * D_ + kt * 64 + kq * 4);
            float4 bv = *(const float4*)(W + (size_t)(bn * 128 + row) * D_ + kt * 64 + kq * 4);
            u16x4 ah, al, bh, bl;
            cvt4(av, &ah, &al);
            cvt4(bv, &bh, &bl);
            int off = row * 128 + ((((kq >> 1) ^ (row & 7))) << 4) + ((kq & 1) << 3);
            *(u16x4*)(AH + off) = ah; *(u16x4*)(AL + off) = al;
            *(u16x4*)(BH + off) = bh; *(u16x4*)(BL + off) = bl;
        }
        __syncthreads();
        #pragma unroll
        for (int ks = 0; ks < 2; ++ks) {
            bf16x8 aH[4], aL[4], bH[4], bL[4];
            #pragma unroll
            for (int mt = 0; mt < 4; ++mt) {
                int row = wm * 64 + mt * 16 + lr;
                int off = row * 128 + (((ks * 4 + lk) ^ (row & 7)) << 4);
                aH[mt] = *(const bf16x8*)(AH + off);
                aL[mt] = *(const bf16x8*)(AL + off);
            }
            #pragma unroll
            for (int nt = 0; nt < 4; ++nt) {
                int row = wn * 64 + nt * 16 + lr;
                int off = row * 128 + (((ks * 4 + lk) ^ (row & 7)) << 4);
                bH[nt] = *(const bf16x8*)(BH + off);
                bL[nt] = *(const bf16x8*)(BL + off);
            }
            #pragma unroll
            for (int mt = 0; mt < 4; ++mt)
                #pragma unroll
                for (int nt = 0; nt < 4; ++nt) {
                    acc[mt][nt] = __builtin_amdgcn_mfma_f32_16x16x32_bf16(aH[mt], bH[nt], acc[mt][nt], 0, 0, 0);
                    acc[mt][nt] = __builtin_amdgcn_mfma_f32_16x16x32_bf16(aH[mt], bL[nt], acc[mt][nt], 0, 0, 0);
                    acc[mt][nt] = __builtin_amdgcn_mfma_f32_16x16x32_bf16(aL[mt], bH[nt], acc[mt][nt], 0, 0, 0);
                }
        }
    }
    #pragma unroll
    for (int mt = 0; mt < 4; ++mt)
        #pragma unroll
        for (int r = 0; r < 4; ++r) {
            int m = bm * 128 + wm * 64 + mt * 16 + lk * 4 + r;
            int b = m >> 13, t = m & 8191;
            float bet = beta[(size_t)(b * H_ + bn) * T_ + t];
            size_t ob = ((size_t)(b * H_ + bn) * T_ + t) * HD_;
            #pragma unroll
            for (int nt = 0; nt < 4; ++nt)
                vb[ob + wn * 64 + nt * 16 + lr] = acc[mt][nt][r] * bet;
        }
}

// =====================================================================
// Kernel 3: chunk — dots, attn(bf16), M, A=M^{-1}, kcd-neg (hi/lo),
//   v' = A@v (f32 in place), kdwT[dk][c] = k^T * gamma^{63-c} hi(/lo).
// =====================================================================
__launch_bounds__(256, 2)
__global__ void chunk_kernel(const unsigned short* __restrict__ khi,
                             const unsigned short* __restrict__ klo,
                             float* __restrict__ vb,
                             const float* __restrict__ beta_g,
                             const float* __restrict__ decay,
                             unsigned short* __restrict__ attn_g,
                             unsigned short* __restrict__ kcdhi_g,
                             unsigned short* __restrict__ kcdlo_g,
                             unsigned short* __restrict__ kdwh_g,
                             unsigned short* __restrict__ kdwl_g) {
    extern __shared__ char cs[];
    char*  sk = cs;                      // [64][128] f32 swz (32KB); later reused for v
    float* sa = (float*)(cs + 32768);    // [64][64] A
    float* sm = (float*)(cs + 49152);    // [64][64] M
    __shared__ float sb[64];
    __shared__ float swgt[64];

    int cid = blockIdx.x;
    int bh = cid >> 7, cn = cid & 127;
    int h = bh & 7;
    int tid = threadIdx.x;
    float dec = decay[h];
    float sg = 1.0f / (1.0f + expf(-dec));
    float lg = logf(sg);
    size_t base = (size_t)cid * 8192;

    #pragma unroll
    for (int lq = 0; lq < 4; ++lq) {
        int f = tid + lq * 256;
        int c = f >> 4, u0 = (f & 15) << 1;
        u16x8 hh = *(const u16x8*)(khi + base + (size_t)f * 8);
        u16x8 ll = *(const u16x8*)(klo + base + (size_t)f * 8);
        float4 v0 = {bf2f(hh[0]) + bf2f(ll[0]), bf2f(hh[1]) + bf2f(ll[1]),
                     bf2f(hh[2]) + bf2f(ll[2]), bf2f(hh[3]) + bf2f(ll[3])};
        float4 v1 = {bf2f(hh[4]) + bf2f(ll[4]), bf2f(hh[5]) + bf2f(ll[5]),
                     bf2f(hh[6]) + bf2f(ll[6]), bf2f(hh[7]) + bf2f(ll[7])};
        *r512(sk, c, u0)     = v0;
        *r512(sk, c, u0 + 1) = v1;
    }
    if (tid < 64) {
        float bv = beta_g[(size_t)bh * T_ + cn * 64 + tid];
        sb[tid] = bv;
        swgt[tid] = bv * expf((float)(tid + 1) * lg);
    }
    __syncthreads();

    int bi = tid >> 4, bj = tid & 15;
    float dacc[4][4] = {};
    for (int u = 0; u < 32; ++u) {
        float4 ka[4], kc[4];
        #pragma unroll
        for (int i = 0; i < 4; ++i) ka[i] = *r512(sk, bi * 4 + i, u);
        #pragma unroll
        for (int j = 0; j < 4; ++j) kc[j] = *r512(sk, bj + 16 * j, u);
        #pragma unroll
        for (int i = 0; i < 4; ++i)
            #pragma unroll
            for (int j = 0; j < 4; ++j)
                dacc[i][j] += dot4(ka[i], kc[j]);
    }
    size_t abase = (size_t)cid * 4096;
    #pragma unroll
    for (int i = 0; i < 4; ++i) {
        int gi = bi * 4 + i;
        #pragma unroll
        for (int j = 0; j < 4; ++j) {
            int gj = bj + 16 * j;
            float dv = dacc[i][j];
            float dfac = expf((float)(gi - gj) * lg);
            attn_g[abase + (size_t)gi * 64 + gj] = (gi >= gj) ? f2bf(dv * dfac) : (unsigned short)0;
            sm[gi * 64 + gj] = (gj < gi) ? sb[gi] * dv * dfac : ((gi == gj) ? 1.f : 0.f);
        }
    }
    __syncthreads();

    if (tid < 64) {
        int j = tid;
        for (int i = 0; i < j; ++i) sa[i * 64 + j] = 0.f;
        sa[j * 64 + j] = 1.f;
        for (int i = j + 1; i < 64; ++i) {
            float s = 0.f;
            for (int p = j; p < i; ++p) s += sm[i * 64 + p] * sa[p * 64 + j];
            sa[i * 64 + j] = -s;
        }
    }
    __syncthreads();

    int ti = tid >> 4, te = tid & 15;
    {   // kcd(negated) hi/lo
        float ko[4][8] = {};
        for (int p = 0; p < 64; ++p) {
            float w = swgt[p];
            float4 k0 = *r512(sk, p, te * 2);
            float4 k1 = *r512(sk, p, te * 2 + 1);
            float kv[8] = {k0.x, k0.y, k0.z, k0.w, k1.x, k1.y, k1.z, k1.w};
            float a0 = sa[(ti * 4 + 0) * 64 + p] * w;
            float a1 = sa[(ti * 4 + 1) * 64 + p] * w;
            float a2 = sa[(ti * 4 + 2) * 64 + p] * w;
            float a3 = sa[(ti * 4 + 3) * 64 + p] * w;
            #pragma unroll
            for (int e = 0; e < 8; ++e) {
                ko[0][e] = fmaf(a0, kv[e], ko[0][e]);
                ko[1][e] = fmaf(a1, kv[e], ko[1][e]);
                ko[2][e] = fmaf(a2, kv[e], ko[2][e]);
                ko[3][e] = fmaf(a3, kv[e], ko[3][e]);
            }
        }
        #pragma unroll
        for (int i = 0; i < 4; ++i) {
            u16x8 hh, ll;
            #pragma unroll
            for (int e = 0; e < 8; ++e) {
                float t = -ko[i][e];
                unsigned short hv = f2bf(t);
                hh[e] = hv;
                ll[e] = f2bf(t - bf2f(hv));
            }
            size_t off = base + (size_t)(ti * 4 + i) * 128 + te * 8;
            *(u16x8*)(kcdhi_g + off) = hh;
            *(u16x8*)(kcdlo_g + off) = ll;
        }
    }

    // ---- kdwT emission: kdwT[dk][c] = k[c][dk] * gamma^{63-c}, hi(+lo). ----
    {
        int dk = tid >> 1, ch = (tid & 1) * 32;
        #pragma unroll
        for (int q = 0; q < 4; ++q) {
            u16x8 th, tl;
            #pragma unroll
            for (int j = 0; j < 8; ++j) {
                int c = ch + q * 8 + j;
                float kv = ld_sk(sk, c, dk) * expf((float)(63 - c) * lg);
                unsigned short hv = f2bf(kv);
                th[j] = hv;
                tl[j] = f2bf(kv - bf2f(hv));
            }
            size_t off = base + (size_t)dk * 64 + ch + q * 8;
            *(u16x8*)(kdwh_g + off) = th;
            if (kdwl_g) *(u16x8*)(kdwl_g + off) = tl;
        }
    }
    __syncthreads();

    #pragma unroll
    for (int lq = 0; lq < 8; ++lq) {
        int f = tid + lq * 256;
        int r = f >> 5, u = f & 31;
        *r512(sk, r, u) = ((const float4*)(vb + base))[f];
    }
    __syncthreads();

    {   // v' = A @ v (in place)
        float vo[4][8] = {};
        for (int p = 0; p < 64; ++p) {
            float4 v0 = *r512(sk, p, te * 2);
            float4 v1 = *r512(sk, p, te * 2 + 1);
            float vv[8] = {v0.x, v0.y, v0.z, v0.w, v1.x, v1.y, v1.z, v1.w};
            float a0 = sa[(ti * 4 + 0) * 64 + p];
            float a1 = sa[(ti * 4 + 1) * 64 + p];
            float a2 = sa[(ti * 4 + 2) * 64 + p];
            float a3 = sa[(ti * 4 + 3) * 64 + p];
            #pragma unroll
            for (int e = 0; e < 8; ++e) {
                vo[0][e] = fmaf(a0, vv[e], vo[0][e]);
                vo[1][e] = fmaf(a1, vv[e], vo[1][e]);
                vo[2][e] = fmaf(a2, vv[e], vo[2][e]);
                vo[3][e] = fmaf(a3, vv[e], vo[3][e]);
            }
        }
        #pragma unroll
        for (int i = 0; i < 4; ++i) {
            float4 lo = {vo[i][0], vo[i][1], vo[i][2], vo[i][3]};
            float4 hi = {vo[i][4], vo[i][5], vo[i][6], vo[i][7]};
            size_t off = base + (size_t)(ti * 4 + i) * 128 + te * 8;
            *(float4*)(vb + off)     = lo;
            *(float4*)(vb + off + 4) = hi;
        }
    }
}

// =====================================================================
// Kernel 4: scan v6 — v3's 8-wave role-split structure + direct-global
// A-fragments (no KP staging, no W-publish; gamma folded into kdwT).
// grid 128 = 16 bh x 8 e-strips(16), 512 thr, static LDS 12KB.
// o written f32 IN PLACE over v' (vb).
// =====================================================================
__launch_bounds__(512, 1)
__global__ void scan_kernel(const unsigned short* __restrict__ khi,
                            const unsigned short* __restrict__ klo,
                            float* __restrict__ vb,
                            const unsigned short* __restrict__ kcdh,
                            const unsigned short* __restrict__ kcdl,
                            const unsigned short* __restrict__ att,
                            const unsigned short* __restrict__ kdwh,
                            const unsigned short* __restrict__ kdwl,
                            const float* __restrict__ decay) {
    __shared__ char SH[4096];   // S^T hi [e:16][dk:128] bf16, unit-swizzled
    __shared__ char SL[4096];
    __shared__ char VH[2048];   // vnew^T [e:16][c:64]
    __shared__ char VL[2048];

    int bid = blockIdx.x;                 // 0..127
    int bh = ((bid >> 6) << 3) + (bid & 7);   // same-h blocks share an XCD
    int strip = (bid >> 3) & 7;
    int e0 = strip * 16;
    int tid = threadIdx.x;
    int w = tid >> 6, l = tid & 63, lr = l & 15, lk = l >> 4;
    int grp = w >> 2, cw = w & 3;
    float dec = decay[bh & 7];
    float sg = 1.0f / (1.0f + expf(-dec));
    float lg = logf(sg);
    float g64 = expf(64.f * lg);
    float dev4[4];
    #pragma unroll
    for (int r = 0; r < 4; ++r)
        dev4[r] = expf((float)(cw * 16 + lk * 4 + r + 1) * lg);   // used by grp1
    const bool haveLo = (kdwl != nullptr);

    f32x4 Sacc = (f32x4){0.f, 0.f, 0.f, 0.f};  // S^T dk-tile w, e cols 0..15

    // persistent per-chunk regs (role-split, prefetched one chunk ahead)
    bf16x8 fH[4], fL[4];             // grp0: kcd ; grp1: k
    bf16x8 atA[2];                   // grp1 only
    f32x4 vnA;                       // grp0 only

    // ---- prologue: prefetch chunk 0 ----
    {
        size_t nb = (size_t)bh * N_ * 8192;
        size_t na = (size_t)bh * N_ * 4096;
        if (grp == 0) {
            #pragma unroll
            for (int ks = 0; ks < 4; ++ks) {
                size_t off = nb + (size_t)(cw * 16 + lr) * 128 + ks * 32 + lk * 8;
                fH[ks] = *(const bf16x8*)(kcdh + off);
                fL[ks] = *(const bf16x8*)(kcdl + off);
            }
            #pragma unroll
            for (int r = 0; r < 4; ++r)
                vnA[r] = vb[nb + (size_t)(cw * 16 + lk * 4 + r) * 128 + e0 + lr];
        } else {
            #pragma unroll
            for (int ks = 0; ks < 4; ++ks) {
                size_t off = nb + (size_t)(cw * 16 + lr) * 128 + ks * 32 + lk * 8;
                fH[ks] = *(const bf16x8*)(khi + off);
                fL[ks] = *(const bf16x8*)(klo + off);
            }
            #pragma unroll
            for (int ks2 = 0; ks2 < 2; ++ks2)
                atA[ks2] = *(const bf16x8*)(att + na + (size_t)(cw * 16 + lr) * 64 + ks2 * 32 + lk * 8);
        }
    }

    for (int cn = 0; cn < N_; ++cn) {
        size_t cb8 = ((size_t)bh * N_ + cn) * 8192;

        // ---- publish S hi/lo (wave w owns dk cols [16w,16w+16)) ----
        {
            u16x4 h4, l4;
            #pragma unroll
            for (int r = 0; r < 4; ++r) {
                unsigned short hv = f2bf(Sacc[r]);
                h4[r] = hv;
                l4[r] = f2bf(Sacc[r] - bf2f(hv));
            }
            int unit = 2 * w + (lk >> 1);    // 0..15
            int off = lr * 256 + ((unit ^ (lr & 7)) << 4) + ((lk & 1) << 3);
            *(u16x4*)(SH + off) = h4;
            *(u16x4*)(SL + off) = l4;
        }
        __syncthreads();   // bar1: S ready

        // ---- S B-fragments ----
        bf16x8 BH[4], BL[4];
        #pragma unroll
        for (int ks = 0; ks < 4; ++ks) {
            int off = lr * 256 + (((ks * 4 + lk) ^ (lr & 7)) << 4);
            BH[ks] = *(const bf16x8*)(SH + off);
            BL[ks] = *(const bf16x8*)(SL + off);
        }
        f32x4 acc1, acc2;
        if (grp == 0) {
            // ---- M1: vnew = v' + (-kcd)@S, 2 chains; publish ----
            acc1 = vnA; acc2 = (f32x4){0.f, 0.f, 0.f, 0.f};
            __builtin_amdgcn_s_setprio(1);
            #pragma unroll
            for (int ks = 0; ks < 2; ++ks) {
                acc1 = __builtin_amdgcn_mfma_f32_16x16x32_bf16(fH[ks], BH[ks], acc1, 0, 0, 0);
                acc2 = __builtin_amdgcn_mfma_f32_16x16x32_bf16(fH[ks+2], BH[ks+2], acc2, 0, 0, 0);
                acc1 = __builtin_amdgcn_mfma_f32_16x16x32_bf16(fH[ks], BL[ks], acc1, 0, 0, 0);
                acc2 = __builtin_amdgcn_mfma_f32_16x16x32_bf16(fH[ks+2], BL[ks+2], acc2, 0, 0, 0);
                acc1 = __builtin_amdgcn_mfma_f32_16x16x32_bf16(fL[ks], BH[ks], acc1, 0, 0, 0);
                acc2 = __builtin_amdgcn_mfma_f32_16x16x32_bf16(fL[ks+2], BH[ks+2], acc2, 0, 0, 0);
            }
            __builtin_amdgcn_s_setprio(0);
            u16x4 h4, l4;
            #pragma unroll
            for (int r = 0; r < 4; ++r) {
                float vv = acc1[r] + acc2[r];
                unsigned short hv = f2bf(vv);
                h4[r] = hv; l4[r] = f2bf(vv - bf2f(hv));
            }
            int cu = 2 * cw + (lk >> 1);     // 0..7
            int off = lr * 128 + ((cu ^ (lr & 7)) << 4) + ((lk & 1) << 3);
            *(u16x4*)(VH + off) = h4;  *(u16x4*)(VL + off) = l4;
        } else {
            // ---- M2a: k@S, 2 chains ----
            acc1 = (f32x4){0.f, 0.f, 0.f, 0.f}; acc2 = acc1;
            __builtin_amdgcn_s_setprio(1);
            #pragma unroll
            for (int ks = 0; ks < 2; ++ks) {
                acc1 = __builtin_amdgcn_mfma_f32_16x16x32_bf16(fH[ks], BH[ks], acc1, 0, 0, 0);
                acc2 = __builtin_amdgcn_mfma_f32_16x16x32_bf16(fH[ks+2], BH[ks+2], acc2, 0, 0, 0);
                acc1 = __builtin_amdgcn_mfma_f32_16x16x32_bf16(fH[ks], BL[ks], acc1, 0, 0, 0);
                acc2 = __builtin_amdgcn_mfma_f32_16x16x32_bf16(fH[ks+2], BL[ks+2], acc2, 0, 0, 0);
                acc1 = __builtin_amdgcn_mfma_f32_16x16x32_bf16(fL[ks], BH[ks], acc1, 0, 0, 0);
                acc2 = __builtin_amdgcn_mfma_f32_16x16x32_bf16(fL[ks+2], BH[ks+2], acc2, 0, 0, 0);
            }
            __builtin_amdgcn_s_setprio(0);
        }
        __syncthreads();   // bar2: vnew visible

        // ---- vnew B-fragments (all waves: M2b and M3 both use them) ----
        bf16x8 VHf[2], VLf[2];
        #pragma unroll
        for (int ks2 = 0; ks2 < 2; ++ks2) {
            int off = lr * 128 + (((ks2 * 4 + lk) ^ (lr & 7)) << 4);
            VHf[ks2] = *(const bf16x8*)(VH + off);
            VLf[ks2] = *(const bf16x8*)(VL + off);
        }
        // ---- kdwT A-frags for CURRENT chunk (this wave's dk-tile w) ----
        bf16x8 tH[2], tL[2];
        #pragma unroll
        for (int ks2 = 0; ks2 < 2; ++ks2) {
            size_t off = cb8 + (size_t)(w * 16 + lr) * 64 + ks2 * 32 + lk * 8;
            tH[ks2] = *(const bf16x8*)(kdwh + off);
            if (haveLo) tL[ks2] = *(const bf16x8*)(kdwl + off);
        }
        if (grp == 1) {
            // ---- M2b: o = dev*(k@S) + att@vnew ; store f32 over v' ----
            f32x4 om;
            #pragma unroll
            for (int r = 0; r < 4; ++r) om[r] = (acc1[r] + acc2[r]) * dev4[r];
            #pragma unroll
            for (int ks2 = 0; ks2 < 2; ++ks2) {
                om = __builtin_amdgcn_mfma_f32_16x16x32_bf16(atA[ks2], VHf[ks2], om, 0, 0, 0);
                om = __builtin_amdgcn_mfma_f32_16x16x32_bf16(atA[ks2], VLf[ks2], om, 0, 0, 0);
            }
            #pragma unroll
            for (int r = 0; r < 4; ++r)
                vb[cb8 + (size_t)(cw * 16 + lk * 4 + r) * 128 + e0 + lr] = om[r];
        }

        // ---- prefetch chunk cn+1 (role-split; hidden under M3) ----
        if (cn + 1 < N_) {
            size_t nb = ((size_t)bh * N_ + cn + 1) * 8192;
            size_t na = ((size_t)bh * N_ + cn + 1) * 4096;
            if (grp == 0) {
                #pragma unroll
                for (int ks = 0; ks < 4; ++ks) {
                    size_t off = nb + (size_t)(cw * 16 + lr) * 128 + ks * 32 + lk * 8;
                    fH[ks] = *(const bf16x8*)(kcdh + off);
                    fL[ks] = *(const bf16x8*)(kcdl + off);
                }
                #pragma unroll
                for (int r = 0; r < 4; ++r)
                    vnA[r] = vb[nb + (size_t)(cw * 16 + lk * 4 + r) * 128 + e0 + lr];
            } else {
                #pragma unroll
                for (int ks = 0; ks < 4; ++ks) {
                    size_t off = nb + (size_t)(cw * 16 + lr) * 128 + ks * 32 + lk * 8;
                    fH[ks] = *(const bf16x8*)(khi + off);
                    fL[ks] = *(const bf16x8*)(klo + off);
                }
                #pragma unroll
                for (int ks2 = 0; ks2 < 2; ++ks2)
                    atA[ks2] = *(const bf16x8*)(att + na + (size_t)(cw * 16 + lr) * 64 + ks2 * 32 + lk * 8);
            }
        }

        // ---- M3: S = g64*S + kdwT @ vnew (2 chains) ----
        {
            #pragma unroll
            for (int r = 0; r < 4; ++r) Sacc[r] *= g64;
            f32x4 tmp = (f32x4){0.f, 0.f, 0.f, 0.f};
            __builtin_amdgcn_s_setprio(1);
            Sacc = __builtin_amdgcn_mfma_f32_16x16x32_bf16(tH[0], VHf[0], Sacc, 0, 0, 0);
            tmp  = __builtin_amdgcn_mfma_f32_16x16x32_bf16(tH[1], VHf[1], tmp,  0, 0, 0);
            Sacc = __builtin_amdgcn_mfma_f32_16x16x32_bf16(tH[0], VLf[0], Sacc, 0, 0, 0);
            tmp  = __builtin_amdgcn_mfma_f32_16x16x32_bf16(tH[1], VLf[1], tmp,  0, 0, 0);
            if (haveLo) {
                Sacc = __builtin_amdgcn_mfma_f32_16x16x32_bf16(tL[0], VHf[0], Sacc, 0, 0, 0);
                tmp  = __builtin_amdgcn_mfma_f32_16x16x32_bf16(tL[1], VHf[1], tmp,  0, 0, 0);
            }
            __builtin_amdgcn_s_setprio(0);
            #pragma unroll
            for (int r = 0; r < 4; ++r) Sacc[r] += tmp[r];
        }
        // next bar1 orders VH/SH rewrites vs this iteration's readers
    }
}

// =====================================================================
// Kernel 5: final — out = x + o @ W_read^T. o is f32 (in vb), 3-product.
// =====================================================================
__launch_bounds__(256, 2)
__global__ void final_kernel(const float* __restrict__ X, const float* __restrict__ W,
                             const float* __restrict__ OB, float* __restrict__ out) {
    extern __shared__ char gs[];
    char* AH = gs;             // [128][64] bf16 hi, swizzled, 16KB
    char* AL = gs + 16384;
    char* BH = gs + 32768;
    char* BL = gs + 49152;     // 64KB
    int bm = blockIdx.x, bn = blockIdx.y;
    int tid = threadIdx.x;
    int w = tid >> 6, lr = tid & 15, lk = (tid & 63) >> 4;
    int wm = w >> 1, wn = w & 1;

    f32x4 acc[4][4];
    #pragma unroll
    for (int i = 0; i < 4; ++i)
        #pragma unroll
        for (int j = 0; j < 4; ++j) acc[i][j] = (f32x4){0.f, 0.f, 0.f, 0.f};

    for (int kt = 0; kt < 16; ++kt) {
        int hh = kt >> 1, e0g = (kt & 1) * 64;
        __syncthreads();
        #pragma unroll
        for (int q = 0; q < 8; ++q) {
            int f = tid + q * 256;
            int row = f >> 4, kq = f & 15;
            int m = bm * 128 + row;
            int b = m >> 13, t = m & 8191;
            float4 av = *(const float4*)(OB + (((size_t)(b * H_ + hh) * T_ + t) << 7) + e0g + kq * 4);
            float4 bv = *(const float4*)(W + (size_t)(bn * 128 + row) * D_ + kt * 64 + kq * 4);
            u16x4 ah, al, bh, bl;
            cvt4(av, &ah, &al);
            cvt4(bv, &bh, &bl);
            int off = row * 128 + ((((kq >> 1) ^ (row & 7))) << 4) + ((kq & 1) << 3);
            *(u16x4*)(AH + off) = ah; *(u16x4*)(AL + off) = al;
            *(u16x4*)(BH + off) = bh; *(u16x4*)(BL + off) = bl;
        }
        __syncthreads();
        #pragma unroll
        for (int ks = 0; ks < 2; ++ks) {
            bf16x8 aH[4], aL[4], bH[4], bL[4];
            #pragma unroll
            for (int mt = 0; mt < 4; ++mt) {
                int row = wm * 64 + mt * 16 + lr;
                int off = row * 128 + (((ks * 4 + lk) ^ (row & 7)) << 4);
                aH[mt] = *(const bf16x8*)(AH + off);
                aL[mt] = *(const bf16x8*)(AL + off);
            }
            #pragma unroll
            for (int nt = 0; nt < 4; ++nt) {
                int row = wn * 64 + nt * 16 + lr;
                int off = row * 128 + (((ks * 4 + lk) ^ (row & 7)) << 4);
                bH[nt] = *(const bf16x8*)(BH + off);
                bL[nt] = *(const bf16x8*)(BL + off);
            }
            #pragma unroll
            for (int mt = 0; mt < 4; ++mt)
                #pragma unroll
                for (int nt = 0; nt < 4; ++nt) {
                    acc[mt][nt] = __builtin_amdgcn_mfma_f32_16x16x32_bf16(aH[mt], bH[nt], acc[mt][nt], 0, 0, 0);
                    acc[mt][nt] = __builtin_amdgcn_mfma_f32_16x16x32_bf16(aH[mt], bL[nt], acc[mt][nt], 0, 0, 0);
                    acc[mt][nt] = __builtin_amdgcn_mfma_f32_16x16x32_bf16(aL[mt], bH[nt], acc[mt][nt], 0, 0, 0);
                }
        }
    }
    #pragma unroll
    for (int mt = 0; mt < 4; ++mt)
        #pragma unroll
        for (int r = 0; r < 4; ++r) {
            int m = bm * 128 + wm * 64 + mt * 16 + lk * 4 + r;
            size_t xo = (size_t)m * D_ + bn * 128;
            #pragma unroll
            for (int nt = 0; nt < 4; ++nt) {
                int n = wn * 64 + nt * 16 + lr;
                out[xo + n] = X[xo + n] + acc[mt][nt][r];
            }
        }
}

// =====================================================================
extern "C" void kernel_launch(void* const* d_in, const int* in_sizes, int n_in,
                              void* d_out, int out_size, void* d_ws, size_t ws_size,
                              hipStream_t stream) {
    const float* X   = (const float*)d_in[0];
    const float* Ww  = (const float*)d_in[1];
    const float* Wr  = (const float*)d_in[2];
    const float* Wb  = (const float*)d_in[3];
    const float* dec = (const float*)d_in[4];

    // workspace layout (bytes). Base = 252,182,528 (proven). kdwl optional.
    char* ws = (char*)d_ws;
    unsigned short* khi  = (unsigned short*)(ws);                 // 32MB [c][dk] hi
    unsigned short* klo  = (unsigned short*)(ws + 33554432);      // 32MB
    float*          vb   = (float*)(ws + 67108864);               // 64MB  v -> v' -> o (f32)
    unsigned short* kcdh = (unsigned short*)(ws + 134217728);     // 32MB
    unsigned short* kcdl = (unsigned short*)(ws + 167772160);     // 32MB
    unsigned short* attn = (unsigned short*)(ws + 201326592);     // 16MB
    float*          beta = (float*)(ws + 218103808);              // 0.5MB
    unsigned short* kdwh = (unsigned short*)(ws + 218628096);     // 32MB [dk][c]*gamma hi
    unsigned short* kdwl = (ws_size >= 285736960ull)
                         ? (unsigned short*)(ws + 252182528)      // 32MB lo (if room)
                         : (unsigned short*)nullptr;
    if (ws_size < 252182528ull) return;

    hipFuncSetAttribute((const void*)vproj_kernel, hipFuncAttributeMaxDynamicSharedMemorySize, 65536);
    hipFuncSetAttribute((const void*)chunk_kernel, hipFuncAttributeMaxDynamicSharedMemorySize, 65536);
    hipFuncSetAttribute((const void*)final_kernel, hipFuncAttributeMaxDynamicSharedMemorySize, 65536);

    hipLaunchKernelGGL(prep_kernel, dim3(B_ * T_), dim3(256), 0, stream, X, Wb, khi, klo, beta);
    hipLaunchKernelGGL(vproj_kernel, dim3(128, 8), dim3(256), 65536, stream, X, Ww, beta, vb);
    hipLaunchKernelGGL(chunk_kernel, dim3(B_ * H_ * N_), dim3(256), 65536, stream,
                       khi, klo, vb, beta, dec, attn, kcdh, kcdl, kdwh, kdwl);
    hipLaunchKernelGGL(scan_kernel, dim3(128), dim3(512), 0, stream,
                       khi, klo, vb, kcdh, kcdl, attn, kdwh, kdwl, dec);
    hipLaunchKernelGGL(final_kernel, dim3(128, 8), dim3(256), 65536, stream, X, Wr, vb, (float*)d_out);
}

// Round 10
// 1075.078 us; speedup vs baseline: 2.8808x; 1.0089x over previous
//
#include <hip/hip_runtime.h>
#include <stdint.h>

#define DEV static __device__ __forceinline__

typedef float          f32x4  __attribute__((ext_vector_type(4)));
typedef short          bf16x8 __attribute__((ext_vector_type(8)));
typedef unsigned short u16x4  __attribute__((ext_vector_type(4)));
typedef unsigned short u16x8  __attribute__((ext_vector_type(8)));

#define B_   2
#define T_   8192
#define D_   1024
#define H_   8
#define HD_  128
#define N_   128   /* chunks per (b,h) */

DEV float dot4(const float4& a, const float4& b) {
    return a.x * b.x + a.y * b.y + a.z * b.z + a.w * b.w;
}
DEV unsigned short f2bf(float f) {
    union { float f; unsigned u; } v; v.f = f;
    unsigned r = (v.u + 0x7fffu + ((v.u >> 16) & 1u)) >> 16;
    return (unsigned short)r;
}
DEV float bf2f(unsigned short u) {
    union { unsigned u; float f; } v; v.u = ((unsigned)u) << 16;
    return v.f;
}
DEV void cvt4(const float4 v, u16x4* h, u16x4* l) {
    const float* p = (const float*)&v;
    #pragma unroll
    for (int i = 0; i < 4; ++i) {
        unsigned short hv = f2bf(p[i]);
        (*h)[i] = hv;
        (*l)[i] = f2bf(p[i] - bf2f(hv));
    }
}
// LDS-ordering-only barrier: waits this wave's ds ops, does NOT drain vmcnt,
// so prefetched global loads / o-stores stay in flight across the barrier.
DEV void bar_lgkm() {
    asm volatile("s_waitcnt lgkmcnt(0)" ::: "memory");
    __builtin_amdgcn_s_barrier();
}
// Swizzled LDS rows of 512B (128 f32); swizzle per 16B unit: unit ^= (row&7).
DEV float4* r512(char* base, int r, int u) {
    return (float4*)(base + (r << 9) + ((u << 4) ^ ((r & 7) << 4)));
}
DEV float ld_sk(char* base, int c, int dk) {  // scalar read from swizzled [c][dk] f32 tile
    return *(float*)(base + (c << 9) + ((((dk >> 2) << 4) ^ ((c & 7) << 4)) + ((dk & 3) << 2)));
}

// =====================================================================
// Kernel 1: prep — L2-normalized k per head -> bf16 hi/lo [c][dk]; beta.
// =====================================================================
__launch_bounds__(256)
__global__ void prep_kernel(const float* __restrict__ X, const float* __restrict__ Wb,
                            unsigned short* __restrict__ khi, unsigned short* __restrict__ klo,
                            float* __restrict__ beta) {
    int bt = blockIdx.x;
    int b = bt >> 13, t = bt & 8191;
    __shared__ float xrow[D_];
    const float* xp = X + (size_t)bt * D_;
    for (int i = threadIdx.x; i < D_; i += 256) xrow[i] = xp[i];
    __syncthreads();
    int w = threadIdx.x >> 6, lane = threadIdx.x & 63;
    for (int h = w; h < H_; h += 4) {
        const float* xh = xrow + h * HD_;
        float a0 = xh[lane], a1 = xh[lane + 64];
        float s = a0 * a0 + a1 * a1;
        #pragma unroll
        for (int off = 32; off > 0; off >>= 1) s += __shfl_xor(s, off);
        float rn = 1.0f / fmaxf(sqrtf(s), 1e-12f);
        const float* wbh = Wb + (size_t)h * D_;
        float bs = 0.f;
        for (int i = lane; i < D_; i += 64) bs += xrow[i] * wbh[i];
        #pragma unroll
        for (int off = 32; off > 0; off >>= 1) bs += __shfl_xor(bs, off);
        float bet = 1.0f / (1.0f + expf(-bs));
        size_t kbase = ((size_t)(b * H_ + h) * T_ + t) * HD_;
        float x0 = a0 * rn, x1 = a1 * rn;
        unsigned short h0 = f2bf(x0), h1 = f2bf(x1);
        khi[kbase + lane]      = h0;
        khi[kbase + lane + 64] = h1;
        klo[kbase + lane]      = f2bf(x0 - bf2f(h0));
        klo[kbase + lane + 64] = f2bf(x1 - bf2f(h1));
        if (lane == 0) beta[(size_t)(b * H_ + h) * T_ + t] = bet;
    }
}

// =====================================================================
// Kernel 2: vproj — v = beta*(x @ W_write^T) via split-bf16 MFMA (f32 out)
// =====================================================================
__launch_bounds__(256, 2)
__global__ void vproj_kernel(const float* __restrict__ X, const float* __restrict__ W,
                             const float* __restrict__ beta, float* __restrict__ vb) {
    extern __shared__ char gs[];
    char* AH = gs;             // [128][64] bf16 hi, swizzled, 16KB
    char* AL = gs + 16384;
    char* BH = gs + 32768;
    char* BL = gs + 49152;     // 64KB
    int bm = blockIdx.x, bn = blockIdx.y;
    int tid = threadIdx.x;
    int w = tid >> 6, lr = tid & 15, lk = (tid & 63) >> 4;
    int wm = w >> 1, wn = w & 1;

    f32x4 acc[4][4];
    #pragma unroll
    for (int i = 0; i < 4; ++i)
        #pragma unroll
        for (int j = 0; j < 4; ++j) acc[i][j] = (f32x4){0.f, 0.f, 0.f, 0.f};

    for (int kt = 0; kt < 16; ++kt) {
        __syncthreads();
        #pragma unroll
        for (int q = 0; q < 8; ++q) {
            int f = tid + q * 256;
            int row = f >> 4, kq = f & 15;
            float4 av = *(const float4*)(X + (size_t)(bm * 128 + row) * D_ + kt * 64 + kq * 4);
            float4 bv = *(const float4*)(W + (size_t)(bn * 128 + row) * D_ + kt * 64 + kq * 4);
            u16x4 ah, al, bh, bl;
            cvt4(av, &ah, &al);
            cvt4(bv, &bh, &bl);
            int off = row * 128 + ((((kq >> 1) ^ (row & 7))) << 4) + ((kq & 1) << 3);
            *(u16x4*)(AH + off) = ah; *(u16x4*)(AL + off) = al;
            *(u16x4*)(BH + off) = bh; *(u16x4*)(BL + off) = bl;
        }
        __syncthreads();
        #pragma unroll
        for (int ks = 0; ks < 2; ++ks) {
            bf16x8 aH[4], aL[4], bH[4], bL[4];
            #pragma unroll
            for (int mt = 0; mt < 4; ++mt) {
                int row = wm * 64 + mt * 16 + lr;
                int off = row * 128 + (((ks * 4 + lk) ^ (row & 7)) << 4);
                aH[mt] = *(const bf16x8*)(AH + off);
                aL[mt] = *(const bf16x8*)(AL + off);
            }
            #pragma unroll
            for (int nt = 0; nt < 4; ++nt) {
                int row = wn * 64 + nt * 16 + lr;
                int off = row * 128 + (((ks * 4 + lk) ^ (row & 7)) << 4);
                bH[nt] = *(const bf16x8*)(BH + off);
                bL[nt] = *(const bf16x8*)(BL + off);
            }
            #pragma unroll
            for (int mt = 0; mt < 4; ++mt)
                #pragma unroll
                for (int nt = 0; nt < 4; ++nt) {
                    acc[mt][nt] = __builtin_amdgcn_mfma_f32_16x16x32_bf16(aH[mt], bH[nt], acc[mt][nt], 0, 0, 0);
                    acc[mt][nt] = __builtin_amdgcn_mfma_f32_16x16x32_bf16(aH[mt], bL[nt], acc[mt][nt], 0, 0, 0);
                    acc[mt][nt] = __builtin_amdgcn_mfma_f32_16x16x32_bf16(aL[mt], bH[nt], acc[mt][nt], 0, 0, 0);
                }
        }
    }
    #pragma unroll
    for (int mt = 0; mt < 4; ++mt)
        #pragma unroll
        for (int r = 0; r < 4; ++r) {
            int m = bm * 128 + wm * 64 + mt * 16 + lk * 4 + r;
            int b = m >> 13, t = m & 8191;
            float bet = beta[(size_t)(b * H_ + bn) * T_ + t];
            size_t ob = ((size_t)(b * H_ + bn) * T_ + t) * HD_;
            #pragma unroll
            for (int nt = 0; nt < 4; ++nt)
                vb[ob + wn * 64 + nt * 16 + lr] = acc[mt][nt][r] * bet;
        }
}

// =====================================================================
// Kernel 3: chunk — dots, attn(bf16), M, A=M^{-1}, kcd-neg (hi/lo),
//   v' = A@v (f32 in place), kdwT[dk][c] = k^T * gamma^{63-c} hi(/lo).
// =====================================================================
__launch_bounds__(256, 2)
__global__ void chunk_kernel(const unsigned short* __restrict__ khi,
                             const unsigned short* __restrict__ klo,
                             float* __restrict__ vb,
                             const float* __restrict__ beta_g,
                             const float* __restrict__ decay,
                             unsigned short* __restrict__ attn_g,
                             unsigned short* __restrict__ kcdhi_g,
                             unsigned short* __restrict__ kcdlo_g,
                             unsigned short* __restrict__ kdwh_g,
                             unsigned short* __restrict__ kdwl_g) {
    extern __shared__ char cs[];
    char*  sk = cs;                      // [64][128] f32 swz (32KB); later reused for v
    float* sa = (float*)(cs + 32768);    // [64][64] A
    float* sm = (float*)(cs + 49152);    // [64][64] M
    __shared__ float sb[64];
    __shared__ float swgt[64];

    int cid = blockIdx.x;
    int bh = cid >> 7, cn = cid & 127;
    int h = bh & 7;
    int tid = threadIdx.x;
    float dec = decay[h];
    float sg = 1.0f / (1.0f + expf(-dec));
    float lg = logf(sg);
    size_t base = (size_t)cid * 8192;

    #pragma unroll
    for (int lq = 0; lq < 4; ++lq) {
        int f = tid + lq * 256;
        int c = f >> 4, u0 = (f & 15) << 1;
        u16x8 hh = *(const u16x8*)(khi + base + (size_t)f * 8);
        u16x8 ll = *(const u16x8*)(klo + base + (size_t)f * 8);
        float4 v0 = {bf2f(hh[0]) + bf2f(ll[0]), bf2f(hh[1]) + bf2f(ll[1]),
                     bf2f(hh[2]) + bf2f(ll[2]), bf2f(hh[3]) + bf2f(ll[3])};
        float4 v1 = {bf2f(hh[4]) + bf2f(ll[4]), bf2f(hh[5]) + bf2f(ll[5]),
                     bf2f(hh[6]) + bf2f(ll[6]), bf2f(hh[7]) + bf2f(ll[7])};
        *r512(sk, c, u0)     = v0;
        *r512(sk, c, u0 + 1) = v1;
    }
    if (tid < 64) {
        float bv = beta_g[(size_t)bh * T_ + cn * 64 + tid];
        sb[tid] = bv;
        swgt[tid] = bv * expf((float)(tid + 1) * lg);
    }
    __syncthreads();

    int bi = tid >> 4, bj = tid & 15;
    float dacc[4][4] = {};
    for (int u = 0; u < 32; ++u) {
        float4 ka[4], kc[4];
        #pragma unroll
        for (int i = 0; i < 4; ++i) ka[i] = *r512(sk, bi * 4 + i, u);
        #pragma unroll
        for (int j = 0; j < 4; ++j) kc[j] = *r512(sk, bj + 16 * j, u);
        #pragma unroll
        for (int i = 0; i < 4; ++i)
            #pragma unroll
            for (int j = 0; j < 4; ++j)
                dacc[i][j] += dot4(ka[i], kc[j]);
    }
    size_t abase = (size_t)cid * 4096;
    #pragma unroll
    for (int i = 0; i < 4; ++i) {
        int gi = bi * 4 + i;
        #pragma unroll
        for (int j = 0; j < 4; ++j) {
            int gj = bj + 16 * j;
            float dv = dacc[i][j];
            float dfac = expf((float)(gi - gj) * lg);
            attn_g[abase + (size_t)gi * 64 + gj] = (gi >= gj) ? f2bf(dv * dfac) : (unsigned short)0;
            sm[gi * 64 + gj] = (gj < gi) ? sb[gi] * dv * dfac : ((gi == gj) ? 1.f : 0.f);
        }
    }
    __syncthreads();

    if (tid < 64) {
        int j = tid;
        for (int i = 0; i < j; ++i) sa[i * 64 + j] = 0.f;
        sa[j * 64 + j] = 1.f;
        for (int i = j + 1; i < 64; ++i) {
            float s = 0.f;
            for (int p = j; p < i; ++p) s += sm[i * 64 + p] * sa[p * 64 + j];
            sa[i * 64 + j] = -s;
        }
    }
    __syncthreads();

    int ti = tid >> 4, te = tid & 15;
    {   // kcd(negated) hi/lo
        float ko[4][8] = {};
        for (int p = 0; p < 64; ++p) {
            float w = swgt[p];
            float4 k0 = *r512(sk, p, te * 2);
            float4 k1 = *r512(sk, p, te * 2 + 1);
            float kv[8] = {k0.x, k0.y, k0.z, k0.w, k1.x, k1.y, k1.z, k1.w};
            float a0 = sa[(ti * 4 + 0) * 64 + p] * w;
            float a1 = sa[(ti * 4 + 1) * 64 + p] * w;
            float a2 = sa[(ti * 4 + 2) * 64 + p] * w;
            float a3 = sa[(ti * 4 + 3) * 64 + p] * w;
            #pragma unroll
            for (int e = 0; e < 8; ++e) {
                ko[0][e] = fmaf(a0, kv[e], ko[0][e]);
                ko[1][e] = fmaf(a1, kv[e], ko[1][e]);
                ko[2][e] = fmaf(a2, kv[e], ko[2][e]);
                ko[3][e] = fmaf(a3, kv[e], ko[3][e]);
            }
        }
        #pragma unroll
        for (int i = 0; i < 4; ++i) {
            u16x8 hh, ll;
            #pragma unroll
            for (int e = 0; e < 8; ++e) {
                float t = -ko[i][e];
                unsigned short hv = f2bf(t);
                hh[e] = hv;
                ll[e] = f2bf(t - bf2f(hv));
            }
            size_t off = base + (size_t)(ti * 4 + i) * 128 + te * 8;
            *(u16x8*)(kcdhi_g + off) = hh;
            *(u16x8*)(kcdlo_g + off) = ll;
        }
    }

    // ---- kdwT emission: kdwT[dk][c] = k[c][dk] * gamma^{63-c}, hi(+lo). ----
    {
        int dk = tid >> 1, ch = (tid & 1) * 32;
        #pragma unroll
        for (int q = 0; q < 4; ++q) {
            u16x8 th, tl;
            #pragma unroll
            for (int j = 0; j < 8; ++j) {
                int c = ch + q * 8 + j;
                float kv = ld_sk(sk, c, dk) * expf((float)(63 - c) * lg);
                unsigned short hv = f2bf(kv);
                th[j] = hv;
                tl[j] = f2bf(kv - bf2f(hv));
            }
            size_t off = base + (size_t)dk * 64 + ch + q * 8;
            *(u16x8*)(kdwh_g + off) = th;
            if (kdwl_g) *(u16x8*)(kdwl_g + off) = tl;
        }
    }
    __syncthreads();

    #pragma unroll
    for (int lq = 0; lq < 8; ++lq) {
        int f = tid + lq * 256;
        int r = f >> 5, u = f & 31;
        *r512(sk, r, u) = ((const float4*)(vb + base))[f];
    }
    __syncthreads();

    {   // v' = A @ v (in place)
        float vo[4][8] = {};
        for (int p = 0; p < 64; ++p) {
            float4 v0 = *r512(sk, p, te * 2);
            float4 v1 = *r512(sk, p, te * 2 + 1);
            float vv[8] = {v0.x, v0.y, v0.z, v0.w, v1.x, v1.y, v1.z, v1.w};
            float a0 = sa[(ti * 4 + 0) * 64 + p];
            float a1 = sa[(ti * 4 + 1) * 64 + p];
            float a2 = sa[(ti * 4 + 2) * 64 + p];
            float a3 = sa[(ti * 4 + 3) * 64 + p];
            #pragma unroll
            for (int e = 0; e < 8; ++e) {
                vo[0][e] = fmaf(a0, vv[e], vo[0][e]);
                vo[1][e] = fmaf(a1, vv[e], vo[1][e]);
                vo[2][e] = fmaf(a2, vv[e], vo[2][e]);
                vo[3][e] = fmaf(a3, vv[e], vo[3][e]);
            }
        }
        #pragma unroll
        for (int i = 0; i < 4; ++i) {
            float4 lo = {vo[i][0], vo[i][1], vo[i][2], vo[i][3]};
            float4 hi = {vo[i][4], vo[i][5], vo[i][6], vo[i][7]};
            size_t off = base + (size_t)(ti * 4 + i) * 128 + te * 8;
            *(float4*)(vb + off)     = lo;
            *(float4*)(vb + off + 4) = hi;
        }
    }
}

// =====================================================================
// Kernel 4: scan v7 — v6 structure, but: (a) lgkm-only barriers (no
// vmcnt drain -> prefetch/stores stay in flight), (b) kdwT fragment
// loads hoisted to top of iteration.
// grid 128 = 16 bh x 8 e-strips(16), 512 thr, static LDS 12KB.
// =====================================================================
__launch_bounds__(512, 1)
__global__ void scan_kernel(const unsigned short* __restrict__ khi,
                            const unsigned short* __restrict__ klo,
                            float* __restrict__ vb,
                            const unsigned short* __restrict__ kcdh,
                            const unsigned short* __restrict__ kcdl,
                            const unsigned short* __restrict__ att,
                            const unsigned short* __restrict__ kdwh,
                            const unsigned short* __restrict__ kdwl,
                            const float* __restrict__ decay) {
    __shared__ char SH[4096];   // S^T hi [e:16][dk:128] bf16, unit-swizzled
    __shared__ char SL[4096];
    __shared__ char VH[2048];   // vnew^T [e:16][c:64]
    __shared__ char VL[2048];

    int bid = blockIdx.x;                 // 0..127
    int bh = ((bid >> 6) << 3) + (bid & 7);   // same-h blocks share an XCD
    int strip = (bid >> 3) & 7;
    int e0 = strip * 16;
    int tid = threadIdx.x;
    int w = tid >> 6, l = tid & 63, lr = l & 15, lk = l >> 4;
    int grp = w >> 2, cw = w & 3;
    float dec = decay[bh & 7];
    float sg = 1.0f / (1.0f + expf(-dec));
    float lg = logf(sg);
    float g64 = expf(64.f * lg);
    float dev4[4];
    #pragma unroll
    for (int r = 0; r < 4; ++r)
        dev4[r] = expf((float)(cw * 16 + lk * 4 + r + 1) * lg);   // used by grp1
    const bool haveLo = (kdwl != nullptr);

    f32x4 Sacc = (f32x4){0.f, 0.f, 0.f, 0.f};  // S^T dk-tile w, e cols 0..15

    // persistent per-chunk regs (role-split, prefetched one chunk ahead)
    bf16x8 fH[4], fL[4];             // grp0: kcd ; grp1: k
    bf16x8 atA[2];                   // grp1 only
    f32x4 vnA;                       // grp0 only

    // ---- prologue: prefetch chunk 0 ----
    {
        size_t nb = (size_t)bh * N_ * 8192;
        size_t na = (size_t)bh * N_ * 4096;
        if (grp == 0) {
            #pragma unroll
            for (int ks = 0; ks < 4; ++ks) {
                size_t off = nb + (size_t)(cw * 16 + lr) * 128 + ks * 32 + lk * 8;
                fH[ks] = *(const bf16x8*)(kcdh + off);
                fL[ks] = *(const bf16x8*)(kcdl + off);
            }
            #pragma unroll
            for (int r = 0; r < 4; ++r)
                vnA[r] = vb[nb + (size_t)(cw * 16 + lk * 4 + r) * 128 + e0 + lr];
        } else {
            #pragma unroll
            for (int ks = 0; ks < 4; ++ks) {
                size_t off = nb + (size_t)(cw * 16 + lr) * 128 + ks * 32 + lk * 8;
                fH[ks] = *(const bf16x8*)(khi + off);
                fL[ks] = *(const bf16x8*)(klo + off);
            }
            #pragma unroll
            for (int ks2 = 0; ks2 < 2; ++ks2)
                atA[ks2] = *(const bf16x8*)(att + na + (size_t)(cw * 16 + lr) * 64 + ks2 * 32 + lk * 8);
        }
    }

    for (int cn = 0; cn < N_; ++cn) {
        size_t cb8 = ((size_t)bh * N_ + cn) * 8192;

        // ---- kdwT A-frags for CURRENT chunk, issued EARLY (used in M3) ----
        bf16x8 tH[2], tL[2];
        #pragma unroll
        for (int ks2 = 0; ks2 < 2; ++ks2) {
            size_t off = cb8 + (size_t)(w * 16 + lr) * 64 + ks2 * 32 + lk * 8;
            tH[ks2] = *(const bf16x8*)(kdwh + off);
            if (haveLo) tL[ks2] = *(const bf16x8*)(kdwl + off);
        }

        // ---- publish S hi/lo (wave w owns dk cols [16w,16w+16)) ----
        {
            u16x4 h4, l4;
            #pragma unroll
            for (int r = 0; r < 4; ++r) {
                unsigned short hv = f2bf(Sacc[r]);
                h4[r] = hv;
                l4[r] = f2bf(Sacc[r] - bf2f(hv));
            }
            int unit = 2 * w + (lk >> 1);    // 0..15
            int off = lr * 256 + ((unit ^ (lr & 7)) << 4) + ((lk & 1) << 3);
            *(u16x4*)(SH + off) = h4;
            *(u16x4*)(SL + off) = l4;
        }
        bar_lgkm();   // bar1: S ready (LDS-order only; vmem stays in flight)

        // ---- S B-fragments ----
        bf16x8 BH[4], BL[4];
        #pragma unroll
        for (int ks = 0; ks < 4; ++ks) {
            int off = lr * 256 + (((ks * 4 + lk) ^ (lr & 7)) << 4);
            BH[ks] = *(const bf16x8*)(SH + off);
            BL[ks] = *(const bf16x8*)(SL + off);
        }
        f32x4 acc1, acc2;
        if (grp == 0) {
            // ---- M1: vnew = v' + (-kcd)@S, 2 chains; publish ----
            acc1 = vnA; acc2 = (f32x4){0.f, 0.f, 0.f, 0.f};
            __builtin_amdgcn_s_setprio(1);
            #pragma unroll
            for (int ks = 0; ks < 2; ++ks) {
                acc1 = __builtin_amdgcn_mfma_f32_16x16x32_bf16(fH[ks], BH[ks], acc1, 0, 0, 0);
                acc2 = __builtin_amdgcn_mfma_f32_16x16x32_bf16(fH[ks+2], BH[ks+2], acc2, 0, 0, 0);
                acc1 = __builtin_amdgcn_mfma_f32_16x16x32_bf16(fH[ks], BL[ks], acc1, 0, 0, 0);
                acc2 = __builtin_amdgcn_mfma_f32_16x16x32_bf16(fH[ks+2], BL[ks+2], acc2, 0, 0, 0);
                acc1 = __builtin_amdgcn_mfma_f32_16x16x32_bf16(fL[ks], BH[ks], acc1, 0, 0, 0);
                acc2 = __builtin_amdgcn_mfma_f32_16x16x32_bf16(fL[ks+2], BH[ks+2], acc2, 0, 0, 0);
            }
            __builtin_amdgcn_s_setprio(0);
            u16x4 h4, l4;
            #pragma unroll
            for (int r = 0; r < 4; ++r) {
                float vv = acc1[r] + acc2[r];
                unsigned short hv = f2bf(vv);
                h4[r] = hv; l4[r] = f2bf(vv - bf2f(hv));
            }
            int cu = 2 * cw + (lk >> 1);     // 0..7
            int off = lr * 128 + ((cu ^ (lr & 7)) << 4) + ((lk & 1) << 3);
            *(u16x4*)(VH + off) = h4;  *(u16x4*)(VL + off) = l4;
        } else {
            // ---- M2a: k@S, 2 chains ----
            acc1 = (f32x4){0.f, 0.f, 0.f, 0.f}; acc2 = acc1;
            __builtin_amdgcn_s_setprio(1);
            #pragma unroll
            for (int ks = 0; ks < 2; ++ks) {
                acc1 = __builtin_amdgcn_mfma_f32_16x16x32_bf16(fH[ks], BH[ks], acc1, 0, 0, 0);
                acc2 = __builtin_amdgcn_mfma_f32_16x16x32_bf16(fH[ks+2], BH[ks+2], acc2, 0, 0, 0);
                acc1 = __builtin_amdgcn_mfma_f32_16x16x32_bf16(fH[ks], BL[ks], acc1, 0, 0, 0);
                acc2 = __builtin_amdgcn_mfma_f32_16x16x32_bf16(fH[ks+2], BL[ks+2], acc2, 0, 0, 0);
                acc1 = __builtin_amdgcn_mfma_f32_16x16x32_bf16(fL[ks], BH[ks], acc1, 0, 0, 0);
                acc2 = __builtin_amdgcn_mfma_f32_16x16x32_bf16(fL[ks+2], BH[ks+2], acc2, 0, 0, 0);
            }
            __builtin_amdgcn_s_setprio(0);
        }
        bar_lgkm();   // bar2: vnew visible

        // ---- vnew B-fragments (all waves: M2b and M3 both use them) ----
        bf16x8 VHf[2], VLf[2];
        #pragma unroll
        for (int ks2 = 0; ks2 < 2; ++ks2) {
            int off = lr * 128 + (((ks2 * 4 + lk) ^ (lr & 7)) << 4);
            VHf[ks2] = *(const bf16x8*)(VH + off);
            VLf[ks2] = *(const bf16x8*)(VL + off);
        }
        if (grp == 1) {
            // ---- M2b: o = dev*(k@S) + att@vnew ; store f32 over v' ----
            f32x4 om;
            #pragma unroll
            for (int r = 0; r < 4; ++r) om[r] = (acc1[r] + acc2[r]) * dev4[r];
            #pragma unroll
            for (int ks2 = 0; ks2 < 2; ++ks2) {
                om = __builtin_amdgcn_mfma_f32_16x16x32_bf16(atA[ks2], VHf[ks2], om, 0, 0, 0);
                om = __builtin_amdgcn_mfma_f32_16x16x32_bf16(atA[ks2], VLf[ks2], om, 0, 0, 0);
            }
            #pragma unroll
            for (int r = 0; r < 4; ++r)
                vb[cb8 + (size_t)(cw * 16 + lk * 4 + r) * 128 + e0 + lr] = om[r];
        }

        // ---- prefetch chunk cn+1 (role-split; rides across barriers) ----
        if (cn + 1 < N_) {
            size_t nb = ((size_t)bh * N_ + cn + 1) * 8192;
            size_t na = ((size_t)bh * N_ + cn + 1) * 4096;
            if (grp == 0) {
                #pragma unroll
                for (int ks = 0; ks < 4; ++ks) {
                    size_t off = nb + (size_t)(cw * 16 + lr) * 128 + ks * 32 + lk * 8;
                    fH[ks] = *(const bf16x8*)(kcdh + off);
                    fL[ks] = *(const bf16x8*)(kcdl + off);
                }
                #pragma unroll
                for (int r = 0; r < 4; ++r)
                    vnA[r] = vb[nb + (size_t)(cw * 16 + lk * 4 + r) * 128 + e0 + lr];
            } else {
                #pragma unroll
                for (int ks = 0; ks < 4; ++ks) {
                    size_t off = nb + (size_t)(cw * 16 + lr) * 128 + ks * 32 + lk * 8;
                    fH[ks] = *(const bf16x8*)(khi + off);
                    fL[ks] = *(const bf16x8*)(klo + off);
                }
                #pragma unroll
                for (int ks2 = 0; ks2 < 2; ++ks2)
                    atA[ks2] = *(const bf16x8*)(att + na + (size_t)(cw * 16 + lr) * 64 + ks2 * 32 + lk * 8);
            }
        }

        // ---- M3: S = g64*S + kdwT @ vnew (2 chains) ----
        {
            #pragma unroll
            for (int r = 0; r < 4; ++r) Sacc[r] *= g64;
            f32x4 tmp = (f32x4){0.f, 0.f, 0.f, 0.f};
            __builtin_amdgcn_s_setprio(1);
            Sacc = __builtin_amdgcn_mfma_f32_16x16x32_bf16(tH[0], VHf[0], Sacc, 0, 0, 0);
            tmp  = __builtin_amdgcn_mfma_f32_16x16x32_bf16(tH[1], VHf[1], tmp,  0, 0, 0);
            Sacc = __builtin_amdgcn_mfma_f32_16x16x32_bf16(tH[0], VLf[0], Sacc, 0, 0, 0);
            tmp  = __builtin_amdgcn_mfma_f32_16x16x32_bf16(tH[1], VLf[1], tmp,  0, 0, 0);
            if (haveLo) {
                Sacc = __builtin_amdgcn_mfma_f32_16x16x32_bf16(tL[0], VHf[0], Sacc, 0, 0, 0);
                tmp  = __builtin_amdgcn_mfma_f32_16x16x32_bf16(tL[1], VHf[1], tmp,  0, 0, 0);
            }
            __builtin_amdgcn_s_setprio(0);
            #pragma unroll
            for (int r = 0; r < 4; ++r) Sacc[r] += tmp[r];
        }
        // next bar1 orders VH/SH rewrites vs this iteration's readers
    }
}

// =====================================================================
// Kernel 5: final — out = x + o @ W_read^T. o is f32 (in vb), 3-product.
// =====================================================================
__launch_bounds__(256, 2)
__global__ void final_kernel(const float* __restrict__ X, const float* __restrict__ W,
                             const float* __restrict__ OB, float* __restrict__ out) {
    extern __shared__ char gs[];
    char* AH = gs;             // [128][64] bf16 hi, swizzled, 16KB
    char* AL = gs + 16384;
    char* BH = gs + 32768;
    char* BL = gs + 49152;     // 64KB
    int bm = blockIdx.x, bn = blockIdx.y;
    int tid = threadIdx.x;
    int w = tid >> 6, lr = tid & 15, lk = (tid & 63) >> 4;
    int wm = w >> 1, wn = w & 1;

    f32x4 acc[4][4];
    #pragma unroll
    for (int i = 0; i < 4; ++i)
        #pragma unroll
        for (int j = 0; j < 4; ++j) acc[i][j] = (f32x4){0.f, 0.f, 0.f, 0.f};

    for (int kt = 0; kt < 16; ++kt) {
        int hh = kt >> 1, e0g = (kt & 1) * 64;
        __syncthreads();
        #pragma unroll
        for (int q = 0; q < 8; ++q) {
            int f = tid + q * 256;
            int row = f >> 4, kq = f & 15;
            int m = bm * 128 + row;
            int b = m >> 13, t = m & 8191;
            float4 av = *(const float4*)(OB + (((size_t)(b * H_ + hh) * T_ + t) << 7) + e0g + kq * 4);
            float4 bv = *(const float4*)(W + (size_t)(bn * 128 + row) * D_ + kt * 64 + kq * 4);
            u16x4 ah, al, bh, bl;
            cvt4(av, &ah, &al);
            cvt4(bv, &bh, &bl);
            int off = row * 128 + ((((kq >> 1) ^ (row & 7))) << 4) + ((kq & 1) << 3);
            *(u16x4*)(AH + off) = ah; *(u16x4*)(AL + off) = al;
            *(u16x4*)(BH + off) = bh; *(u16x4*)(BL + off) = bl;
        }
        __syncthreads();
        #pragma unroll
        for (int ks = 0; ks < 2; ++ks) {
            bf16x8 aH[4], aL[4], bH[4], bL[4];
            #pragma unroll
            for (int mt = 0; mt < 4; ++mt) {
                int row = wm * 64 + mt * 16 + lr;
                int off = row * 128 + (((ks * 4 + lk) ^ (row & 7)) << 4);
                aH[mt] = *(const bf16x8*)(AH + off);
                aL[mt] = *(const bf16x8*)(AL + off);
            }
            #pragma unroll
            for (int nt = 0; nt < 4; ++nt) {
                int row = wn * 64 + nt * 16 + lr;
                int off = row * 128 + (((ks * 4 + lk) ^ (row & 7)) << 4);
                bH[nt] = *(const bf16x8*)(BH + off);
                bL[nt] = *(const bf16x8*)(BL + off);
            }
            #pragma unroll
            for (int mt = 0; mt < 4; ++mt)
                #pragma unroll
                for (int nt = 0; nt < 4; ++nt) {
                    acc[mt][nt] = __builtin_amdgcn_mfma_f32_16x16x32_bf16(aH[mt], bH[nt], acc[mt][nt], 0, 0, 0);
                    acc[mt][nt] = __builtin_amdgcn_mfma_f32_16x16x32_bf16(aH[mt], bL[nt], acc[mt][nt], 0, 0, 0);
                    acc[mt][nt] = __builtin_amdgcn_mfma_f32_16x16x32_bf16(aL[mt], bH[nt], acc[mt][nt], 0, 0, 0);
                }
        }
    }
    #pragma unroll
    for (int mt = 0; mt < 4; ++mt)
        #pragma unroll
        for (int r = 0; r < 4; ++r) {
            int m = bm * 128 + wm * 64 + mt * 16 + lk * 4 + r;
            size_t xo = (size_t)m * D_ + bn * 128;
            #pragma unroll
            for (int nt = 0; nt < 4; ++nt) {
                int n = wn * 64 + nt * 16 + lr;
                out[xo + n] = X[xo + n] + acc[mt][nt][r];
            }
        }
}

// =====================================================================
extern "C" void kernel_launch(void* const* d_in, const int* in_sizes, int n_in,
                              void* d_out, int out_size, void* d_ws, size_t ws_size,
                              hipStream_t stream) {
    const float* X   = (const float*)d_in[0];
    const float* Ww  = (const float*)d_in[1];
    const float* Wr  = (const float*)d_in[2];
    const float* Wb  = (const float*)d_in[3];
    const float* dec = (const float*)d_in[4];

    // workspace layout (bytes). Base = 252,182,528 (proven). kdwl optional.
    char* ws = (char*)d_ws;
    unsigned short* khi  = (unsigned short*)(ws);                 // 32MB [c][dk] hi
    unsigned short* klo  = (unsigned short*)(ws + 33554432);      // 32MB
    float*          vb   = (float*)(ws + 67108864);               // 64MB  v -> v' -> o (f32)
    unsigned short* kcdh = (unsigned short*)(ws + 134217728);     // 32MB
    unsigned short* kcdl = (unsigned short*)(ws + 167772160);     // 32MB
    unsigned short* attn = (unsigned short*)(ws + 201326592);     // 16MB
    float*          beta = (float*)(ws + 218103808);              // 0.5MB
    unsigned short* kdwh = (unsigned short*)(ws + 218628096);     // 32MB [dk][c]*gamma hi
    unsigned short* kdwl = (ws_size >= 285736960ull)
                         ? (unsigned short*)(ws + 252182528)      // 32MB lo (if room)
                         : (unsigned short*)nullptr;
    if (ws_size < 252182528ull) return;

    hipFuncSetAttribute((const void*)vproj_kernel, hipFuncAttributeMaxDynamicSharedMemorySize, 65536);
    hipFuncSetAttribute((const void*)chunk_kernel, hipFuncAttributeMaxDynamicSharedMemorySize, 65536);
    hipFuncSetAttribute((const void*)final_kernel, hipFuncAttributeMaxDynamicSharedMemorySize, 65536);

    hipLaunchKernelGGL(prep_kernel, dim3(B_ * T_), dim3(256), 0, stream, X, Wb, khi, klo, beta);
    hipLaunchKernelGGL(vproj_kernel, dim3(128, 8), dim3(256), 65536, stream, X, Ww, beta, vb);
    hipLaunchKernelGGL(chunk_kernel, dim3(B_ * H_ * N_), dim3(256), 65536, stream,
                       khi, klo, vb, beta, dec, attn, kcdh, kcdl, kdwh, kdwl);
    hipLaunchKernelGGL(scan_kernel, dim3(128), dim3(512), 0, stream,
                       khi, klo, vb, kcdh, kcdl, attn, kdwh, kdwl, dec);
    hipLaunchKernelGGL(final_kernel, dim3(128, 8), dim3(256), 65536, stream, X, Wr, vb, (float*)d_out);
}

// Round 11
// 961.986 us; speedup vs baseline: 3.2194x; 1.1176x over previous
//
#include <hip/hip_runtime.h>
#include <stdint.h>

#define DEV static __device__ __forceinline__

typedef float          f32x4  __attribute__((ext_vector_type(4)));
typedef short          bf16x8 __attribute__((ext_vector_type(8)));
typedef unsigned short u16x4  __attribute__((ext_vector_type(4)));
typedef unsigned short u16x8  __attribute__((ext_vector_type(8)));

#define B_   2
#define T_   8192
#define D_   1024
#define H_   8
#define HD_  128
#define N_   128   /* chunks per (b,h) */

DEV float dot4(const float4& a, const float4& b) {
    return a.x * b.x + a.y * b.y + a.z * b.z + a.w * b.w;
}
DEV unsigned short f2bf(float f) {
    union { float f; unsigned u; } v; v.f = f;
    unsigned r = (v.u + 0x7fffu + ((v.u >> 16) & 1u)) >> 16;
    return (unsigned short)r;
}
DEV float bf2f(unsigned short u) {
    union { unsigned u; float f; } v; v.u = ((unsigned)u) << 16;
    return v.f;
}
DEV void cvt4(const float4 v, u16x4* h, u16x4* l) {
    const float* p = (const float*)&v;
    #pragma unroll
    for (int i = 0; i < 4; ++i) {
        unsigned short hv = f2bf(p[i]);
        (*h)[i] = hv;
        (*l)[i] = f2bf(p[i] - bf2f(hv));
    }
}
// LDS-ordering-only barrier (no vmcnt drain).
DEV void bar_lgkm() {
    asm volatile("s_waitcnt lgkmcnt(0)" ::: "memory");
    __builtin_amdgcn_s_barrier();
}
// Swizzled LDS rows of 512B (128 f32); swizzle per 16B unit: unit ^= (row&7).
DEV float4* r512(char* base, int r, int u) {
    return (float4*)(base + (r << 9) + ((u << 4) ^ ((r & 7) << 4)));
}
DEV float ld_sk(char* base, int c, int dk) {
    return *(float*)(base + (c << 9) + ((((dk >> 2) << 4) ^ ((c & 7) << 4)) + ((dk & 3) << 2)));
}

// =====================================================================
// Kernel 0: split — f32 array -> bf16 hi/lo planes (for weights).
// grid: n/(256*8) blocks x 256.
// =====================================================================
__launch_bounds__(256)
__global__ void split_kernel(const float* __restrict__ src,
                             unsigned short* __restrict__ h,
                             unsigned short* __restrict__ l) {
    size_t base = ((size_t)blockIdx.x * 256 + threadIdx.x) * 8;
    float4 a = *(const float4*)(src + base);
    float4 b = *(const float4*)(src + base + 4);
    u16x4 ah, al, bh, bl;
    cvt4(a, &ah, &al);
    cvt4(b, &bh, &bl);
    *(u16x4*)(h + base)     = ah;
    *(u16x4*)(h + base + 4) = bh;
    *(u16x4*)(l + base)     = al;
    *(u16x4*)(l + base + 4) = bl;
}

// =====================================================================
// Kernel 1: prep — L2-normalized k per head -> bf16 hi/lo [c][dk]; beta.
// =====================================================================
__launch_bounds__(256)
__global__ void prep_kernel(const float* __restrict__ X, const float* __restrict__ Wb,
                            unsigned short* __restrict__ khi, unsigned short* __restrict__ klo,
                            float* __restrict__ beta) {
    int bt = blockIdx.x;
    int b = bt >> 13, t = bt & 8191;
    __shared__ float xrow[D_];
    const float* xp = X + (size_t)bt * D_;
    for (int i = threadIdx.x; i < D_; i += 256) xrow[i] = xp[i];
    __syncthreads();
    int w = threadIdx.x >> 6, lane = threadIdx.x & 63;
    for (int h = w; h < H_; h += 4) {
        const float* xh = xrow + h * HD_;
        float a0 = xh[lane], a1 = xh[lane + 64];
        float s = a0 * a0 + a1 * a1;
        #pragma unroll
        for (int off = 32; off > 0; off >>= 1) s += __shfl_xor(s, off);
        float rn = 1.0f / fmaxf(sqrtf(s), 1e-12f);
        const float* wbh = Wb + (size_t)h * D_;
        float bs = 0.f;
        for (int i = lane; i < D_; i += 64) bs += xrow[i] * wbh[i];
        #pragma unroll
        for (int off = 32; off > 0; off >>= 1) bs += __shfl_xor(bs, off);
        float bet = 1.0f / (1.0f + expf(-bs));
        size_t kbase = ((size_t)(b * H_ + h) * T_ + t) * HD_;
        float x0 = a0 * rn, x1 = a1 * rn;
        unsigned short h0 = f2bf(x0), h1 = f2bf(x1);
        khi[kbase + lane]      = h0;
        khi[kbase + lane + 64] = h1;
        klo[kbase + lane]      = f2bf(x0 - bf2f(h0));
        klo[kbase + lane + 64] = f2bf(x1 - bf2f(h1));
        if (lane == 0) beta[(size_t)(b * H_ + h) * T_ + t] = bet;
    }
}

// =====================================================================
// Kernel 2: vproj — v = beta*(x @ W_write^T); A cvt-staged, B pre-split.
// =====================================================================
__launch_bounds__(256, 2)
__global__ void vproj_kernel(const float* __restrict__ X,
                             const unsigned short* __restrict__ Wh,
                             const unsigned short* __restrict__ Wl,
                             const float* __restrict__ beta, float* __restrict__ vb) {
    extern __shared__ char gs[];
    char* AH = gs;             // [128][64] bf16 hi, swizzled, 16KB
    char* AL = gs + 16384;
    char* BH = gs + 32768;
    char* BL = gs + 49152;     // 64KB
    int bm = blockIdx.x, bn = blockIdx.y;
    int tid = threadIdx.x;
    int w = tid >> 6, lr = tid & 15, lk = (tid & 63) >> 4;
    int wm = w >> 1, wn = w & 1;

    f32x4 acc[4][4];
    #pragma unroll
    for (int i = 0; i < 4; ++i)
        #pragma unroll
        for (int j = 0; j < 4; ++j) acc[i][j] = (f32x4){0.f, 0.f, 0.f, 0.f};

    for (int kt = 0; kt < 16; ++kt) {
        __syncthreads();
        #pragma unroll
        for (int q = 0; q < 8; ++q) {
            int f = tid + q * 256;
            int row = f >> 4, kq = f & 15;
            float4 av = *(const float4*)(X + (size_t)(bm * 128 + row) * D_ + kt * 64 + kq * 4);
            u16x4 ah, al;
            cvt4(av, &ah, &al);
            int off = row * 128 + ((((kq >> 1) ^ (row & 7))) << 4) + ((kq & 1) << 3);
            *(u16x4*)(AH + off) = ah; *(u16x4*)(AL + off) = al;
        }
        #pragma unroll
        for (int q = 0; q < 4; ++q) {
            int f = tid + q * 256;
            int row = f >> 3, u = f & 7;
            size_t go = (size_t)(bn * 128 + row) * D_ + kt * 64 + u * 8;
            int off = row * 128 + ((u ^ (row & 7)) << 4);
            *(u16x8*)(BH + off) = *(const u16x8*)(Wh + go);
            *(u16x8*)(BL + off) = *(const u16x8*)(Wl + go);
        }
        __syncthreads();
        #pragma unroll
        for (int ks = 0; ks < 2; ++ks) {
            bf16x8 aH[4], aL[4], bH[4], bL[4];
            #pragma unroll
            for (int mt = 0; mt < 4; ++mt) {
                int row = wm * 64 + mt * 16 + lr;
                int off = row * 128 + (((ks * 4 + lk) ^ (row & 7)) << 4);
                aH[mt] = *(const bf16x8*)(AH + off);
                aL[mt] = *(const bf16x8*)(AL + off);
            }
            #pragma unroll
            for (int nt = 0; nt < 4; ++nt) {
                int row = wn * 64 + nt * 16 + lr;
                int off = row * 128 + (((ks * 4 + lk) ^ (row & 7)) << 4);
                bH[nt] = *(const bf16x8*)(BH + off);
                bL[nt] = *(const bf16x8*)(BL + off);
            }
            #pragma unroll
            for (int mt = 0; mt < 4; ++mt)
                #pragma unroll
                for (int nt = 0; nt < 4; ++nt) {
                    acc[mt][nt] = __builtin_amdgcn_mfma_f32_16x16x32_bf16(aH[mt], bH[nt], acc[mt][nt], 0, 0, 0);
                    acc[mt][nt] = __builtin_amdgcn_mfma_f32_16x16x32_bf16(aH[mt], bL[nt], acc[mt][nt], 0, 0, 0);
                    acc[mt][nt] = __builtin_amdgcn_mfma_f32_16x16x32_bf16(aL[mt], bH[nt], acc[mt][nt], 0, 0, 0);
                }
        }
    }
    #pragma unroll
    for (int mt = 0; mt < 4; ++mt)
        #pragma unroll
        for (int r = 0; r < 4; ++r) {
            int m = bm * 128 + wm * 64 + mt * 16 + lk * 4 + r;
            int b = m >> 13, t = m & 8191;
            float bet = beta[(size_t)(b * H_ + bn) * T_ + t];
            size_t ob = ((size_t)(b * H_ + bn) * T_ + t) * HD_;
            #pragma unroll
            for (int nt = 0; nt < 4; ++nt)
                vb[ob + wn * 64 + nt * 16 + lr] = acc[mt][nt][r] * bet;
        }
}

// =====================================================================
// Kernel 3: chunk — dots, attn(bf16), M, A=M^{-1}, kcd-neg (hi/lo),
//   v' = A@v (f32 in place), kdwT[dk][c] = k^T * gamma^{63-c} hi(/lo).
// =====================================================================
__launch_bounds__(256, 2)
__global__ void chunk_kernel(const unsigned short* __restrict__ khi,
                             const unsigned short* __restrict__ klo,
                             float* __restrict__ vb,
                             const float* __restrict__ beta_g,
                             const float* __restrict__ decay,
                             unsigned short* __restrict__ attn_g,
                             unsigned short* __restrict__ kcdhi_g,
                             unsigned short* __restrict__ kcdlo_g,
                             unsigned short* __restrict__ kdwh_g,
                             unsigned short* __restrict__ kdwl_g) {
    extern __shared__ char cs[];
    char*  sk = cs;
    float* sa = (float*)(cs + 32768);
    float* sm = (float*)(cs + 49152);
    __shared__ float sb[64];
    __shared__ float swgt[64];

    int cid = blockIdx.x;
    int bh = cid >> 7, cn = cid & 127;
    int h = bh & 7;
    int tid = threadIdx.x;
    float dec = decay[h];
    float sg = 1.0f / (1.0f + expf(-dec));
    float lg = logf(sg);
    size_t base = (size_t)cid * 8192;

    #pragma unroll
    for (int lq = 0; lq < 4; ++lq) {
        int f = tid + lq * 256;
        int c = f >> 4, u0 = (f & 15) << 1;
        u16x8 hh = *(const u16x8*)(khi + base + (size_t)f * 8);
        u16x8 ll = *(const u16x8*)(klo + base + (size_t)f * 8);
        float4 v0 = {bf2f(hh[0]) + bf2f(ll[0]), bf2f(hh[1]) + bf2f(ll[1]),
                     bf2f(hh[2]) + bf2f(ll[2]), bf2f(hh[3]) + bf2f(ll[3])};
        float4 v1 = {bf2f(hh[4]) + bf2f(ll[4]), bf2f(hh[5]) + bf2f(ll[5]),
                     bf2f(hh[6]) + bf2f(ll[6]), bf2f(hh[7]) + bf2f(ll[7])};
        *r512(sk, c, u0)     = v0;
        *r512(sk, c, u0 + 1) = v1;
    }
    if (tid < 64) {
        float bv = beta_g[(size_t)bh * T_ + cn * 64 + tid];
        sb[tid] = bv;
        swgt[tid] = bv * expf((float)(tid + 1) * lg);
    }
    __syncthreads();

    int bi = tid >> 4, bj = tid & 15;
    float dacc[4][4] = {};
    for (int u = 0; u < 32; ++u) {
        float4 ka[4], kc[4];
        #pragma unroll
        for (int i = 0; i < 4; ++i) ka[i] = *r512(sk, bi * 4 + i, u);
        #pragma unroll
        for (int j = 0; j < 4; ++j) kc[j] = *r512(sk, bj + 16 * j, u);
        #pragma unroll
        for (int i = 0; i < 4; ++i)
            #pragma unroll
            for (int j = 0; j < 4; ++j)
                dacc[i][j] += dot4(ka[i], kc[j]);
    }
    size_t abase = (size_t)cid * 4096;
    #pragma unroll
    for (int i = 0; i < 4; ++i) {
        int gi = bi * 4 + i;
        #pragma unroll
        for (int j = 0; j < 4; ++j) {
            int gj = bj + 16 * j;
            float dv = dacc[i][j];
            float dfac = expf((float)(gi - gj) * lg);
            attn_g[abase + (size_t)gi * 64 + gj] = (gi >= gj) ? f2bf(dv * dfac) : (unsigned short)0;
            sm[gi * 64 + gj] = (gj < gi) ? sb[gi] * dv * dfac : ((gi == gj) ? 1.f : 0.f);
        }
    }
    __syncthreads();

    if (tid < 64) {
        int j = tid;
        for (int i = 0; i < j; ++i) sa[i * 64 + j] = 0.f;
        sa[j * 64 + j] = 1.f;
        for (int i = j + 1; i < 64; ++i) {
            float s = 0.f;
            for (int p = j; p < i; ++p) s += sm[i * 64 + p] * sa[p * 64 + j];
            sa[i * 64 + j] = -s;
        }
    }
    __syncthreads();

    int ti = tid >> 4, te = tid & 15;
    {   // kcd(negated) hi/lo
        float ko[4][8] = {};
        for (int p = 0; p < 64; ++p) {
            float w = swgt[p];
            float4 k0 = *r512(sk, p, te * 2);
            float4 k1 = *r512(sk, p, te * 2 + 1);
            float kv[8] = {k0.x, k0.y, k0.z, k0.w, k1.x, k1.y, k1.z, k1.w};
            float a0 = sa[(ti * 4 + 0) * 64 + p] * w;
            float a1 = sa[(ti * 4 + 1) * 64 + p] * w;
            float a2 = sa[(ti * 4 + 2) * 64 + p] * w;
            float a3 = sa[(ti * 4 + 3) * 64 + p] * w;
            #pragma unroll
            for (int e = 0; e < 8; ++e) {
                ko[0][e] = fmaf(a0, kv[e], ko[0][e]);
                ko[1][e] = fmaf(a1, kv[e], ko[1][e]);
                ko[2][e] = fmaf(a2, kv[e], ko[2][e]);
                ko[3][e] = fmaf(a3, kv[e], ko[3][e]);
            }
        }
        #pragma unroll
        for (int i = 0; i < 4; ++i) {
            u16x8 hh, ll;
            #pragma unroll
            for (int e = 0; e < 8; ++e) {
                float t = -ko[i][e];
                unsigned short hv = f2bf(t);
                hh[e] = hv;
                ll[e] = f2bf(t - bf2f(hv));
            }
            size_t off = base + (size_t)(ti * 4 + i) * 128 + te * 8;
            *(u16x8*)(kcdhi_g + off) = hh;
            *(u16x8*)(kcdlo_g + off) = ll;
        }
    }

    {   // kdwT emission
        int dk = tid >> 1, ch = (tid & 1) * 32;
        #pragma unroll
        for (int q = 0; q < 4; ++q) {
            u16x8 th, tl;
            #pragma unroll
            for (int j = 0; j < 8; ++j) {
                int c = ch + q * 8 + j;
                float kv = ld_sk(sk, c, dk) * expf((float)(63 - c) * lg);
                unsigned short hv = f2bf(kv);
                th[j] = hv;
                tl[j] = f2bf(kv - bf2f(hv));
            }
            size_t off = base + (size_t)dk * 64 + ch + q * 8;
            *(u16x8*)(kdwh_g + off) = th;
            if (kdwl_g) *(u16x8*)(kdwl_g + off) = tl;
        }
    }
    __syncthreads();

    #pragma unroll
    for (int lq = 0; lq < 8; ++lq) {
        int f = tid + lq * 256;
        int r = f >> 5, u = f & 31;
        *r512(sk, r, u) = ((const float4*)(vb + base))[f];
    }
    __syncthreads();

    {   // v' = A @ v (in place)
        float vo[4][8] = {};
        for (int p = 0; p < 64; ++p) {
            float4 v0 = *r512(sk, p, te * 2);
            float4 v1 = *r512(sk, p, te * 2 + 1);
            float vv[8] = {v0.x, v0.y, v0.z, v0.w, v1.x, v1.y, v1.z, v1.w};
            float a0 = sa[(ti * 4 + 0) * 64 + p];
            float a1 = sa[(ti * 4 + 1) * 64 + p];
            float a2 = sa[(ti * 4 + 2) * 64 + p];
            float a3 = sa[(ti * 4 + 3) * 64 + p];
            #pragma unroll
            for (int e = 0; e < 8; ++e) {
                vo[0][e] = fmaf(a0, vv[e], vo[0][e]);
                vo[1][e] = fmaf(a1, vv[e], vo[1][e]);
                vo[2][e] = fmaf(a2, vv[e], vo[2][e]);
                vo[3][e] = fmaf(a3, vv[e], vo[3][e]);
            }
        }
        #pragma unroll
        for (int i = 0; i < 4; ++i) {
            float4 lo = {vo[i][0], vo[i][1], vo[i][2], vo[i][3]};
            float4 hi = {vo[i][4], vo[i][5], vo[i][6], vo[i][7]};
            size_t off = base + (size_t)(ti * 4 + i) * 128 + te * 8;
            *(float4*)(vb + off)     = lo;
            *(float4*)(vb + off + 4) = hi;
        }
    }
}

// =====================================================================
// Kernel 4: scan v8 — v7 + 2-deep prefetch (alternating register sets,
// loop unrolled x2). Numerics identical to v6/v7.
// grid 128 = 16 bh x 8 e-strips(16), 512 thr, static LDS 12KB.
// =====================================================================
#define SCAN_PREFETCH(NCH, fH, fL, atA, vnA)                                          \
    {                                                                                 \
        size_t nb = ((size_t)bh * N_ + (NCH)) * 8192;                                 \
        size_t na = ((size_t)bh * N_ + (NCH)) * 4096;                                 \
        if (grp == 0) {                                                               \
            _Pragma("unroll")                                                         \
            for (int ks = 0; ks < 4; ++ks) {                                          \
                size_t off = nb + (size_t)(cw * 16 + lr) * 128 + ks * 32 + lk * 8;    \
                fH[ks] = *(const bf16x8*)(kcdh + off);                                \
                fL[ks] = *(const bf16x8*)(kcdl + off);                                \
            }                                                                         \
            _Pragma("unroll")                                                         \
            for (int r = 0; r < 4; ++r)                                               \
                vnA[r] = vb[nb + (size_t)(cw * 16 + lk * 4 + r) * 128 + e0 + lr];     \
        } else {                                                                      \
            _Pragma("unroll")                                                         \
            for (int ks = 0; ks < 4; ++ks) {                                          \
                size_t off = nb + (size_t)(cw * 16 + lr) * 128 + ks * 32 + lk * 8;    \
                fH[ks] = *(const bf16x8*)(khi + off);                                 \
                fL[ks] = *(const bf16x8*)(klo + off);                                 \
            }                                                                         \
            _Pragma("unroll")                                                         \
            for (int ks2 = 0; ks2 < 2; ++ks2)                                         \
                atA[ks2] = *(const bf16x8*)(att + na + (size_t)(cw * 16 + lr) * 64 + ks2 * 32 + lk * 8); \
        }                                                                             \
    }

#define SCAN_STEP(CN, fH, fL, atA, vnA)                                               \
    {                                                                                 \
        size_t cb8 = ((size_t)bh * N_ + (CN)) * 8192;                                 \
        bf16x8 tH[2], tL[2];                                                          \
        _Pragma("unroll")                                                             \
        for (int ks2 = 0; ks2 < 2; ++ks2) {                                           \
            size_t off = cb8 + (size_t)(w * 16 + lr) * 64 + ks2 * 32 + lk * 8;        \
            tH[ks2] = *(const bf16x8*)(kdwh + off);                                   \
            if (haveLo) tL[ks2] = *(const bf16x8*)(kdwl + off);                       \
        }                                                                             \
        {                                                                             \
            u16x4 h4, l4;                                                             \
            _Pragma("unroll")                                                         \
            for (int r = 0; r < 4; ++r) {                                             \
                unsigned short hv = f2bf(Sacc[r]);                                    \
                h4[r] = hv;                                                           \
                l4[r] = f2bf(Sacc[r] - bf2f(hv));                                     \
            }                                                                         \
            int unit = 2 * w + (lk >> 1);                                             \
            int off = lr * 256 + ((unit ^ (lr & 7)) << 4) + ((lk & 1) << 3);          \
            *(u16x4*)(SH + off) = h4;                                                 \
            *(u16x4*)(SL + off) = l4;                                                 \
        }                                                                             \
        bar_lgkm();                                                                   \
        bf16x8 BH[4], BL[4];                                                          \
        _Pragma("unroll")                                                             \
        for (int ks = 0; ks < 4; ++ks) {                                              \
            int off = lr * 256 + (((ks * 4 + lk) ^ (lr & 7)) << 4);                   \
            BH[ks] = *(const bf16x8*)(SH + off);                                      \
            BL[ks] = *(const bf16x8*)(SL + off);                                      \
        }                                                                             \
        f32x4 acc1, acc2;                                                             \
        if (grp == 0) {                                                               \
            acc1 = vnA; acc2 = (f32x4){0.f, 0.f, 0.f, 0.f};                           \
            __builtin_amdgcn_s_setprio(1);                                            \
            _Pragma("unroll")                                                         \
            for (int ks = 0; ks < 2; ++ks) {                                          \
                acc1 = __builtin_amdgcn_mfma_f32_16x16x32_bf16(fH[ks], BH[ks], acc1, 0, 0, 0);       \
                acc2 = __builtin_amdgcn_mfma_f32_16x16x32_bf16(fH[ks+2], BH[ks+2], acc2, 0, 0, 0);   \
                acc1 = __builtin_amdgcn_mfma_f32_16x16x32_bf16(fH[ks], BL[ks], acc1, 0, 0, 0);       \
                acc2 = __builtin_amdgcn_mfma_f32_16x16x32_bf16(fH[ks+2], BL[ks+2], acc2, 0, 0, 0);   \
                acc1 = __builtin_amdgcn_mfma_f32_16x16x32_bf16(fL[ks], BH[ks], acc1, 0, 0, 0);       \
                acc2 = __builtin_amdgcn_mfma_f32_16x16x32_bf16(fL[ks+2], BH[ks+2], acc2, 0, 0, 0);   \
            }                                                                         \
            __builtin_amdgcn_s_setprio(0);                                            \
            u16x4 h4, l4;                                                             \
            _Pragma("unroll")                                                         \
            for (int r = 0; r < 4; ++r) {                                             \
                float vv = acc1[r] + acc2[r];                                         \
                unsigned short hv = f2bf(vv);                                         \
                h4[r] = hv; l4[r] = f2bf(vv - bf2f(hv));                              \
            }                                                                         \
            int cu = 2 * cw + (lk >> 1);                                              \
            int off = lr * 128 + ((cu ^ (lr & 7)) << 4) + ((lk & 1) << 3);            \
            *(u16x4*)(VH + off) = h4;  *(u16x4*)(VL + off) = l4;                      \
        } else {                                                                      \
            acc1 = (f32x4){0.f, 0.f, 0.f, 0.f}; acc2 = acc1;                          \
            __builtin_amdgcn_s_setprio(1);                                            \
            _Pragma("unroll")                                                         \
            for (int ks = 0; ks < 2; ++ks) {                                          \
                acc1 = __builtin_amdgcn_mfma_f32_16x16x32_bf16(fH[ks], BH[ks], acc1, 0, 0, 0);       \
                acc2 = __builtin_amdgcn_mfma_f32_16x16x32_bf16(fH[ks+2], BH[ks+2], acc2, 0, 0, 0);   \
                acc1 = __builtin_amdgcn_mfma_f32_16x16x32_bf16(fH[ks], BL[ks], acc1, 0, 0, 0);       \
                acc2 = __builtin_amdgcn_mfma_f32_16x16x32_bf16(fH[ks+2], BL[ks+2], acc2, 0, 0, 0);   \
                acc1 = __builtin_amdgcn_mfma_f32_16x16x32_bf16(fL[ks], BH[ks], acc1, 0, 0, 0);       \
                acc2 = __builtin_amdgcn_mfma_f32_16x16x32_bf16(fL[ks+2], BH[ks+2], acc2, 0, 0, 0);   \
            }                                                                         \
            __builtin_amdgcn_s_setprio(0);                                            \
        }                                                                             \
        bar_lgkm();                                                                   \
        bf16x8 VHf[2], VLf[2];                                                        \
        _Pragma("unroll")                                                             \
        for (int ks2 = 0; ks2 < 2; ++ks2) {                                           \
            int off = lr * 128 + (((ks2 * 4 + lk) ^ (lr & 7)) << 4);                  \
            VHf[ks2] = *(const bf16x8*)(VH + off);                                    \
            VLf[ks2] = *(const bf16x8*)(VL + off);                                    \
        }                                                                             \
        if (grp == 1) {                                                               \
            f32x4 om;                                                                 \
            _Pragma("unroll")                                                         \
            for (int r = 0; r < 4; ++r) om[r] = (acc1[r] + acc2[r]) * dev4[r];        \
            _Pragma("unroll")                                                         \
            for (int ks2 = 0; ks2 < 2; ++ks2) {                                       \
                om = __builtin_amdgcn_mfma_f32_16x16x32_bf16(atA[ks2], VHf[ks2], om, 0, 0, 0);  \
                om = __builtin_amdgcn_mfma_f32_16x16x32_bf16(atA[ks2], VLf[ks2], om, 0, 0, 0);  \
            }                                                                         \
            _Pragma("unroll")                                                         \
            for (int r = 0; r < 4; ++r)                                               \
                vb[cb8 + (size_t)(cw * 16 + lk * 4 + r) * 128 + e0 + lr] = om[r];     \
        }                                                                             \
        if ((CN) + 2 < N_) SCAN_PREFETCH((CN) + 2, fH, fL, atA, vnA)                  \
        {                                                                             \
            _Pragma("unroll")                                                         \
            for (int r = 0; r < 4; ++r) Sacc[r] *= g64;                               \
            f32x4 tmp = (f32x4){0.f, 0.f, 0.f, 0.f};                                  \
            __builtin_amdgcn_s_setprio(1);                                            \
            Sacc = __builtin_amdgcn_mfma_f32_16x16x32_bf16(tH[0], VHf[0], Sacc, 0, 0, 0);  \
            tmp  = __builtin_amdgcn_mfma_f32_16x16x32_bf16(tH[1], VHf[1], tmp,  0, 0, 0);  \
            Sacc = __builtin_amdgcn_mfma_f32_16x16x32_bf16(tH[0], VLf[0], Sacc, 0, 0, 0);  \
            tmp  = __builtin_amdgcn_mfma_f32_16x16x32_bf16(tH[1], VLf[1], tmp,  0, 0, 0);  \
            if (haveLo) {                                                             \
                Sacc = __builtin_amdgcn_mfma_f32_16x16x32_bf16(tL[0], VHf[0], Sacc, 0, 0, 0);  \
                tmp  = __builtin_amdgcn_mfma_f32_16x16x32_bf16(tL[1], VHf[1], tmp,  0, 0, 0);  \
            }                                                                         \
            __builtin_amdgcn_s_setprio(0);                                            \
            _Pragma("unroll")                                                         \
            for (int r = 0; r < 4; ++r) Sacc[r] += tmp[r];                            \
        }                                                                             \
    }

__launch_bounds__(512, 1)
__global__ void scan_kernel(const unsigned short* __restrict__ khi,
                            const unsigned short* __restrict__ klo,
                            float* __restrict__ vb,
                            const unsigned short* __restrict__ kcdh,
                            const unsigned short* __restrict__ kcdl,
                            const unsigned short* __restrict__ att,
                            const unsigned short* __restrict__ kdwh,
                            const unsigned short* __restrict__ kdwl,
                            const float* __restrict__ decay) {
    __shared__ char SH[4096];
    __shared__ char SL[4096];
    __shared__ char VH[2048];
    __shared__ char VL[2048];

    int bid = blockIdx.x;
    int bh = ((bid >> 6) << 3) + (bid & 7);
    int strip = (bid >> 3) & 7;
    int e0 = strip * 16;
    int tid = threadIdx.x;
    int w = tid >> 6, l = tid & 63, lr = l & 15, lk = l >> 4;
    int grp = w >> 2, cw = w & 3;
    float dec = decay[bh & 7];
    float sg = 1.0f / (1.0f + expf(-dec));
    float lg = logf(sg);
    float g64 = expf(64.f * lg);
    float dev4[4];
    #pragma unroll
    for (int r = 0; r < 4; ++r)
        dev4[r] = expf((float)(cw * 16 + lk * 4 + r + 1) * lg);
    const bool haveLo = (kdwl != nullptr);

    f32x4 Sacc = (f32x4){0.f, 0.f, 0.f, 0.f};

    // two prefetch register sets (A: even chunks, B: odd chunks)
    bf16x8 fHa[4], fLa[4], atAa[2];
    bf16x8 fHb[4], fLb[4], atAb[2];
    f32x4 vnAa, vnAb;

    SCAN_PREFETCH(0, fHa, fLa, atAa, vnAa)
    SCAN_PREFETCH(1, fHb, fLb, atAb, vnAb)

    for (int cn = 0; cn < N_; cn += 2) {
        SCAN_STEP(cn,     fHa, fLa, atAa, vnAa)
        SCAN_STEP(cn + 1, fHb, fLb, atAb, vnAb)
    }
}

// =====================================================================
// Kernel 5: final — out = x + o @ W_read^T. A = o f32 (cvt), B pre-split.
// =====================================================================
__launch_bounds__(256, 2)
__global__ void final_kernel(const float* __restrict__ X,
                             const unsigned short* __restrict__ Wh,
                             const unsigned short* __restrict__ Wl,
                             const float* __restrict__ OB, float* __restrict__ out) {
    extern __shared__ char gs[];
    char* AH = gs;
    char* AL = gs + 16384;
    char* BH = gs + 32768;
    char* BL = gs + 49152;
    int bm = blockIdx.x, bn = blockIdx.y;
    int tid = threadIdx.x;
    int w = tid >> 6, lr = tid & 15, lk = (tid & 63) >> 4;
    int wm = w >> 1, wn = w & 1;

    f32x4 acc[4][4];
    #pragma unroll
    for (int i = 0; i < 4; ++i)
        #pragma unroll
        for (int j = 0; j < 4; ++j) acc[i][j] = (f32x4){0.f, 0.f, 0.f, 0.f};

    for (int kt = 0; kt < 16; ++kt) {
        int hh = kt >> 1, e0g = (kt & 1) * 64;
        __syncthreads();
        #pragma unroll
        for (int q = 0; q < 8; ++q) {
            int f = tid + q * 256;
            int row = f >> 4, kq = f & 15;
            int m = bm * 128 + row;
            int b = m >> 13, t = m & 8191;
            float4 av = *(const float4*)(OB + (((size_t)(b * H_ + hh) * T_ + t) << 7) + e0g + kq * 4);
            u16x4 ah, al;
            cvt4(av, &ah, &al);
            int off = row * 128 + ((((kq >> 1) ^ (row & 7))) << 4) + ((kq & 1) << 3);
            *(u16x4*)(AH + off) = ah; *(u16x4*)(AL + off) = al;
        }
        #pragma unroll
        for (int q = 0; q < 4; ++q) {
            int f = tid + q * 256;
            int row = f >> 3, u = f & 7;
            size_t go = (size_t)(bn * 128 + row) * D_ + kt * 64 + u * 8;
            int off = row * 128 + ((u ^ (row & 7)) << 4);
            *(u16x8*)(BH + off) = *(const u16x8*)(Wh + go);
            *(u16x8*)(BL + off) = *(const u16x8*)(Wl + go);
        }
        __syncthreads();
        #pragma unroll
        for (int ks = 0; ks < 2; ++ks) {
            bf16x8 aH[4], aL[4], bH[4], bL[4];
            #pragma unroll
            for (int mt = 0; mt < 4; ++mt) {
                int row = wm * 64 + mt * 16 + lr;
                int off = row * 128 + (((ks * 4 + lk) ^ (row & 7)) << 4);
                aH[mt] = *(const bf16x8*)(AH + off);
                aL[mt] = *(const bf16x8*)(AL + off);
            }
            #pragma unroll
            for (int nt = 0; nt < 4; ++nt) {
                int row = wn * 64 + nt * 16 + lr;
                int off = row * 128 + (((ks * 4 + lk) ^ (row & 7)) << 4);
                bH[nt] = *(const bf16x8*)(BH + off);
                bL[nt] = *(const bf16x8*)(BL + off);
            }
            #pragma unroll
            for (int mt = 0; mt < 4; ++mt)
                #pragma unroll
                for (int nt = 0; nt < 4; ++nt) {
                    acc[mt][nt] = __builtin_amdgcn_mfma_f32_16x16x32_bf16(aH[mt], bH[nt], acc[mt][nt], 0, 0, 0);
                    acc[mt][nt] = __builtin_amdgcn_mfma_f32_16x16x32_bf16(aH[mt], bL[nt], acc[mt][nt], 0, 0, 0);
                    acc[mt][nt] = __builtin_amdgcn_mfma_f32_16x16x32_bf16(aL[mt], bH[nt], acc[mt][nt], 0, 0, 0);
                }
        }
    }
    #pragma unroll
    for (int mt = 0; mt < 4; ++mt)
        #pragma unroll
        for (int r = 0; r < 4; ++r) {
            int m = bm * 128 + wm * 64 + mt * 16 + lk * 4 + r;
            size_t xo = (size_t)m * D_ + bn * 128;
            #pragma unroll
            for (int nt = 0; nt < 4; ++nt) {
                int n = wn * 64 + nt * 16 + lr;
                out[xo + n] = X[xo + n] + acc[mt][nt][r];
            }
        }
}

// =====================================================================
extern "C" void kernel_launch(void* const* d_in, const int* in_sizes, int n_in,
                              void* d_out, int out_size, void* d_ws, size_t ws_size,
                              hipStream_t stream) {
    const float* X   = (const float*)d_in[0];
    const float* Ww  = (const float*)d_in[1];
    const float* Wr  = (const float*)d_in[2];
    const float* Wb  = (const float*)d_in[3];
    const float* dec = (const float*)d_in[4];

    // workspace layout (bytes). Base = 252,182,528 (proven). kdwl optional.
    char* ws = (char*)d_ws;
    unsigned short* khi  = (unsigned short*)(ws);                 // 32MB [c][dk] hi
    unsigned short* klo  = (unsigned short*)(ws + 33554432);      // 32MB
    float*          vb   = (float*)(ws + 67108864);               // 64MB  v -> v' -> o (f32)
    unsigned short* kcdh = (unsigned short*)(ws + 134217728);     // 32MB
    unsigned short* kcdl = (unsigned short*)(ws + 167772160);     // 32MB
    unsigned short* attn = (unsigned short*)(ws + 201326592);     // 16MB
    float*          beta = (float*)(ws + 218103808);              // 0.5MB
    unsigned short* kdwh = (unsigned short*)(ws + 218628096);     // 32MB [dk][c]*gamma hi
    unsigned short* kdwl = (ws_size >= 285736960ull)
                         ? (unsigned short*)(ws + 252182528)      // 32MB lo (if room)
                         : (unsigned short*)nullptr;
    if (ws_size < 252182528ull) return;

    // Transient weight-split regions (zero extra workspace):
    //  Ww splits live in the kcd region (dead until chunk_kernel runs).
    //  Wr splits live in the attn region (dead after scan_kernel).
    unsigned short* Wwh = (unsigned short*)(ws + 134217728);      // 2MB
    unsigned short* Wwl = (unsigned short*)(ws + 136314880);      // 2MB
    unsigned short* Wrh = (unsigned short*)(ws + 201326592);      // 2MB
    unsigned short* Wrl = (unsigned short*)(ws + 203423744);      // 2MB

    hipFuncSetAttribute((const void*)vproj_kernel, hipFuncAttributeMaxDynamicSharedMemorySize, 65536);
    hipFuncSetAttribute((const void*)chunk_kernel, hipFuncAttributeMaxDynamicSharedMemorySize, 65536);
    hipFuncSetAttribute((const void*)final_kernel, hipFuncAttributeMaxDynamicSharedMemorySize, 65536);

    hipLaunchKernelGGL(prep_kernel, dim3(B_ * T_), dim3(256), 0, stream, X, Wb, khi, klo, beta);
    hipLaunchKernelGGL(split_kernel, dim3(512), dim3(256), 0, stream, Ww, Wwh, Wwl);
    hipLaunchKernelGGL(vproj_kernel, dim3(128, 8), dim3(256), 65536, stream, X, Wwh, Wwl, beta, vb);
    hipLaunchKernelGGL(chunk_kernel, dim3(B_ * H_ * N_), dim3(256), 65536, stream,
                       khi, klo, vb, beta, dec, attn, kcdh, kcdl, kdwh, kdwl);
    hipLaunchKernelGGL(scan_kernel, dim3(128), dim3(512), 0, stream,
                       khi, klo, vb, kcdh, kcdl, attn, kdwh, kdwl, dec);
    hipLaunchKernelGGL(split_kernel, dim3(512), dim3(256), 0, stream, Wr, Wrh, Wrl);
    hipLaunchKernelGGL(final_kernel, dim3(128, 8), dim3(256), 65536, stream, X, Wrh, Wrl, vb, (float*)d_out);
}